// Round 2
// baseline (228.668 us; speedup 1.0000x reference)
//
#include <hip/hip_runtime.h>
#include <math.h>

// M=512, N=1024, G=16, D=64, C=1024. All GEMM-shaped work on bf16 MFMA 16x16x32.
// pos_bias uses a bf16 hi/lo split MFMA (rounds 4/6: plain bf16 dot error
// ~2e-4 sign-flips entries in log-clip floor rows -> absmax 0.205).
//
// Round 14: r13's fusion was neutral because the GEMM branch's 36KB LDS union
// was charged to ALL blocks (rocprof: LDS_Block_Size 18432x2 waves, Occupancy
// 30%, VALUBusy 55%) -- the 4096 VALU-bound pos blocks lost the occupancy that
// hides their sin->split->mfma dependent chains. Fix: GEMM tiles read MFMA
// fragments DIRECTLY from global (NT layout, K-contiguous: each lane's
// fragment is an aligned 16B load; 4 lanes/row = one 64B line; operands are
// L2-resident ~9MB). No LDS staging, no barriers in the K-loop; LDS shrinks
// to the 9216B epilogue repack buffer, which the pos branch's 7.9KB fits in.
//   1) cast_kernel   : fp32->bf16 casts (exact 4608-block grid)
//   2) posproj_kernel: pos_bias (4096) + direct-fragment GEMMs (768), i%6
//   3) attn_out_kernel: unchanged.
//
// qk_pack[g][p][part][lane][8shorts]: X[row][col], row=p*16+(lane&15),
// col=part*32+(lane>>4)*8+j (g-slice base g*64); p: q rows p=row>>4 (0..31),
// k rows 32+(row-512)>>4 (32..95). vt_pack[g][cc][p][part][lane][8]: p=o>>4.
//
// Workspace (float offsets), total 12,320,768 floats = 49.3 MB:
//   [0,1572864)        : shorts: in_bf (feat 524288 + ctx 1048576), qk_pack (1572864)
//   [1572864,5767168)  : bias_gt  fp16 (16,512,1024)
//   [5767168,9961472)  : bias_ctx fp16 (16,1024,512)
//   [9961472,10485760) : wconv_bf (1048576 s)
//   [10485760,11272192): vt_pack (1572864 s)
//   [11272192,12320768): wfcgt_bf + wfcctx_bf

typedef __attribute__((ext_vector_type(8))) short short8;   // 8 bf16 = 4 VGPRs
typedef __attribute__((ext_vector_type(4))) float floatx4;
typedef __attribute__((ext_vector_type(4))) _Float16 half4;
typedef __attribute__((ext_vector_type(4))) unsigned uint4v;

__device__ inline unsigned short f32_bf16_rne(float x) {
    union { float f; unsigned u; } v; v.f = x;
    unsigned u = v.u;
    return (unsigned short)((u + 0x7fffu + ((u >> 16) & 1u)) >> 16);
}

__device__ inline unsigned fbits(float x) {
    union { float f; unsigned u; } v; v.f = x; return v.u;
}
__device__ inline float bitsf(unsigned u) {
    union { unsigned u; float f; } v; v.u = u; return v.f;
}

__device__ __forceinline__ floatx4 mfma16(short8 a, short8 b, floatx4 c) {
    return __builtin_amdgcn_mfma_f32_16x16x32_bf16(a, b, c, 0, 0, 0);
}

// ---------------------------------------------------------------------------
// 64x64 tile NT bf16 GEMM, fragments DIRECT from global (no LDS staging, no
// K-loop barriers). Lane (m,quad) of wave (qr,qc) reads A[qr+m][k0+kk+quad*8]
// and B[qc+m][k0+kk+quad*8] as aligned short8. One 64-K step prefetched ahead.
// Epilogue (bias + fragment-pack via LDS repack buffer) identical to r10.
// ---------------------------------------------------------------------------
__device__ __forceinline__ void gemm_tile_pack_direct(
    const unsigned short* __restrict__ Ab, int lda,
    const unsigned short* __restrict__ Bb, int ldb, int K,
    unsigned short* __restrict__ out_base,
    const float* __restrict__ biasvec,
    unsigned short* As)                   // 64*72 shorts, epilogue repack only
{
    const int tid = threadIdx.x;
    const int lane = tid & 63;
    const int wave = tid >> 6;
    const int qr = (wave >> 1) * 32;
    const int qc = (wave & 1) * 32;
    const int m = lane & 15;
    const int quad = lane >> 4;

    const unsigned short* Arow0 = Ab + (long long)(qr + m) * lda + quad * 8;
    const unsigned short* Arow1 = Arow0 + 16LL * lda;
    const unsigned short* Brow0 = Bb + (long long)(qc + m) * ldb + quad * 8;
    const unsigned short* Brow1 = Brow0 + 16LL * ldb;

    floatx4 acc00 = {0.f,0.f,0.f,0.f}, acc01 = {0.f,0.f,0.f,0.f};
    floatx4 acc10 = {0.f,0.f,0.f,0.f}, acc11 = {0.f,0.f,0.f,0.f};

    short8 ca0 = *(const short8*)(Arow0);
    short8 ca1 = *(const short8*)(Arow1);
    short8 cb0 = *(const short8*)(Brow0);
    short8 cb1 = *(const short8*)(Brow1);
    short8 da0 = *(const short8*)(Arow0 + 32);
    short8 da1 = *(const short8*)(Arow1 + 32);
    short8 db0 = *(const short8*)(Brow0 + 32);
    short8 db1 = *(const short8*)(Brow1 + 32);

    for (int k0 = 0; ; ) {
        const int kf = k0 + 64;
        short8 ea0, ea1, eb0, eb1, fa0, fa1, fb0, fb1;
        if (kf < K) {
            ea0 = *(const short8*)(Arow0 + kf);
            ea1 = *(const short8*)(Arow1 + kf);
            eb0 = *(const short8*)(Brow0 + kf);
            eb1 = *(const short8*)(Brow1 + kf);
            fa0 = *(const short8*)(Arow0 + kf + 32);
            fa1 = *(const short8*)(Arow1 + kf + 32);
            fb0 = *(const short8*)(Brow0 + kf + 32);
            fb1 = *(const short8*)(Brow1 + kf + 32);
        }
        acc00 = mfma16(ca0, cb0, acc00);
        acc01 = mfma16(ca0, cb1, acc01);
        acc10 = mfma16(ca1, cb0, acc10);
        acc11 = mfma16(ca1, cb1, acc11);
        acc00 = mfma16(da0, db0, acc00);
        acc01 = mfma16(da0, db1, acc01);
        acc10 = mfma16(da1, db0, acc10);
        acc11 = mfma16(da1, db1, acc11);
        k0 = kf;
        if (k0 >= K) break;
        ca0 = ea0; ca1 = ea1; cb0 = eb0; cb1 = eb1;
        da0 = fa0; da1 = fa1; db0 = fb0; db1 = fb1;
    }

    float bias0 = 0.f, bias1 = 0.f;
    if (biasvec) { bias0 = biasvec[qc + m]; bias1 = biasvec[qc + 16 + m]; }

    // waves write disjoint 32x32 quadrants of As; one barrier, then packed out
    const floatx4 accs[2][2] = { {acc00, acc01}, {acc10, acc11} };
    #pragma unroll
    for (int i = 0; i < 2; ++i)
        #pragma unroll
        for (int r = 0; r < 4; ++r) {
            const int lrow = qr + i * 16 + quad * 4 + r;
            #pragma unroll
            for (int j = 0; j < 2; ++j) {
                const int lcol = qc + j * 16 + m;
                float val = accs[i][j][r] + (j ? bias1 : bias0);
                As[lrow * 72 + lcol] = f32_bf16_rne(val);
            }
        }
    __syncthreads();
    #pragma unroll
    for (int h = 0; h < 2; ++h) {
        const int f = h * 2048 + tid * 8;
        const int lanep = (f >> 3) & 63;
        const int part = (f >> 9) & 1;
        const int ploc = f >> 10;
        const int row = ploc * 16 + (lanep & 15);
        const int col = part * 32 + ((lanep >> 4) << 3);
        short8 v8 = *(const short8*)&As[row * 72 + col];
        *(short8*)(out_base + f) = v8;
    }
}

// ---------------------------------------------------------------------------
// Cast-only kernel: exact grid, no guards. 512 + 4*1024 = 4608 blocks.
// ---------------------------------------------------------------------------
__global__ __launch_bounds__(256) void cast_kernel(
    const float* __restrict__ s0, unsigned short* __restrict__ d0,
    const float* __restrict__ s1, unsigned short* __restrict__ d1,
    const float* __restrict__ s2, unsigned short* __restrict__ d2,
    const float* __restrict__ s3, unsigned short* __restrict__ d3,
    const float* __restrict__ s4, unsigned short* __restrict__ d4)
{
    int bc = blockIdx.x;
    const float* s; unsigned short* d;
    if (bc < 512)       { s = s0; d = d0; }
    else if (bc < 1536) { s = s1; d = d1; bc -= 512; }
    else if (bc < 2560) { s = s2; d = d2; bc -= 1536; }
    else if (bc < 3584) { s = s3; d = d3; bc -= 2560; }
    else                { s = s4; d = d4; bc -= 3584; }
    const int idx = (bc * 256 + threadIdx.x) * 4;
    float4 v = *(const float4*)(s + idx);
    ushort4 o;
    o.x = f32_bf16_rne(v.x); o.y = f32_bf16_rne(v.y);
    o.z = f32_bf16_rne(v.z); o.w = f32_bf16_rne(v.w);
    *(ushort4*)(d + idx) = o;
}

// ---------------------------------------------------------------------------
// Fused pos_bias + projvt kernel. 4864 blocks: i%6==0 (i<4608) -> GEMM tile
// (768 of them), everything else -> pos_bias chunk (4096). LDS is now only
// the 9216B repack buffer (pos branch carves its 7.9KB out of it) -> up to
// 8 blocks/CU residency for the VALU-bound pos blocks.
// ---------------------------------------------------------------------------
__global__ __launch_bounds__(256) void posproj_kernel(
    const float* __restrict__ box, const float* __restrict__ ctx_box,
    const float* __restrict__ w_gt, const float* __restrict__ b_gt,
    const float* __restrict__ w_ctx, const float* __restrict__ b_ctx,
    _Float16* __restrict__ bias_gt, _Float16* __restrict__ bias_ctx,
    const unsigned short* __restrict__ in_bf, const unsigned short* __restrict__ wgt,
    const unsigned short* __restrict__ wctx,
    const float* __restrict__ bgt, const float* __restrict__ bctx,
    unsigned short* __restrict__ qk_pack,
    const unsigned short* __restrict__ wconv, unsigned short* __restrict__ vt_pack)
{
    __shared__ __align__(16) unsigned short smem[64 * 72];   // 9216 B
    const int i = blockIdx.x;

    if (i < 4608 && (i % 6) == 0) {      // -------- GEMM branch (768 blocks)
        const int gi = i / 6;            // 0..767
        const int z = gi / 384;
        const int rem = gi - z * 384;
        const int g = rem / 24;
        const int cc = rem - g * 24;     // 0..23
        if (z == 0) {
            const int bm = cc * 64;
            const unsigned short* B = (bm < 512) ? wgt : wctx;
            const float* bias = (bm < 512) ? bgt : bctx;
            gemm_tile_pack_direct(in_bf + (long long)bm * 1024, 1024,
                                  B + (long long)g * 65536, 1024, 1024,
                                  qk_pack + ((long long)g * 96 + cc * 4) * 1024,
                                  bias + g * 64, smem);
        } else {
            gemm_tile_pack_direct(wconv + (long long)g * 65536, 1024,
                                  in_bf + (long long)cc * 65536, 1024, 1024,
                                  vt_pack + ((long long)g * 24 + cc) * 4096,
                                  nullptr, smem);
        }
        return;
    }

    // -------- pos_bias branch: 256 pairs per block (4096 blocks)
    const int pi = (i < 4608) ? (i - i / 6 - 1) : (i - 768);   // 0..4095
    const bool first = (pi < 2048);
    const long long blk = first ? pi : (pi - 2048);
    const float* boxA = first ? box : ctx_box;
    const float* boxB = first ? ctx_box : box;
    const float* w_pos = first ? w_gt : w_ctx;
    const float* b_pos = first ? b_gt : b_ctx;
    _Float16* out = first ? bias_gt : bias_ctx;
    const int shift = first ? 10 : 9;

    // carve pos-branch LDS out of smem (7872 B <= 9216 B)
    unsigned short* BsH = smem;                       // 16*72 shorts
    unsigned short* BsL = smem + 16 * 72;             // 16*72 shorts
    float* posL = (float*)(smem + 32 * 72);           // [p][pair_local], stride 68
    _Float16* stg = (_Float16*)(posL + 4 * 68);       // 16*68 halves

    const int tid = threadIdx.x;

    {   // stage B: w_pos (16x64 fp32) -> bf16 hi + lo (trunc split, packed)
        const int g = tid >> 4;
        const int d = (tid & 15) * 4;
        float4 wv = *(const float4*)(w_pos + g * 64 + d);
        unsigned u0 = fbits(wv.x), u1 = fbits(wv.y);
        unsigned u2 = fbits(wv.z), u3 = fbits(wv.w);
        unsigned r0 = fbits(wv.x - bitsf(u0 & 0xFFFF0000u));
        unsigned r1 = fbits(wv.y - bitsf(u1 & 0xFFFF0000u));
        unsigned r2 = fbits(wv.z - bitsf(u2 & 0xFFFF0000u));
        unsigned r3 = fbits(wv.w - bitsf(u3 & 0xFFFF0000u));
        uint2 hv, lv;
        hv.x = (u0 >> 16) | (u1 & 0xFFFF0000u);
        hv.y = (u2 >> 16) | (u3 & 0xFFFF0000u);
        lv.x = (r0 >> 16) | (r1 & 0xFFFF0000u);
        lv.y = (r2 >> 16) | (r3 & 0xFFFF0000u);
        *(uint2*)&BsH[g * 72 + d] = hv;
        *(uint2*)&BsL[g * 72 + d] = lv;
    }
    __syncthreads();

    const int lane = tid & 63;
    const int w = tid >> 6;
    const int m = lane & 15;
    const int quad = lane >> 4;
    const bool qlow = (quad < 2);
    const float phase = (quad & 1) ? 1.57079632679f : 0.0f;  // cos(t)=sin(t+pi/2)
    const float bpv = b_pos[m];

    // hoist B-fragments (weights) out of the chunk loop
    const unsigned short* bpH = &BsH[m * 72 + quad * 8];
    const unsigned short* bpL = &BsL[m * 72 + quad * 8];
    short8 bH0 = *(const short8*)bpH;
    short8 bH1 = *(const short8*)(bpH + 32);
    short8 bL0 = *(const short8*)bpL;
    short8 bL1 = *(const short8*)(bpL + 32);

    const float w100[8] = {100.f, 42.169650342f, 17.782794100f, 7.498942093f,
                           3.162277660f, 1.333521432f, 0.562341325f, 0.237137371f};
    const long long pbase = blk * 256;

    for (int it = 0; it < 4; ++it) {
        const long long pb = pbase + it * 64;

        // ---- phase A: each pos component computed once (thread (pl, p))
        {
            const int pl = tid & 63;
            const int p = tid >> 6;      // wave-uniform
            const long long pair = pb + pl;
            const int i2 = (int)(pair >> shift);
            const int j2 = (int)(pair & ((1 << shift) - 1));
            float4 ba = *(const float4*)(boxA + i2 * 4);
            float4 bb = *(const float4*)(boxB + j2 * 4);
            float posv;
            if (p == 0) {
                float r = __builtin_amdgcn_rcpf(ba.z - ba.x + 1.f);
                posv = __logf(fmaxf(fabsf((0.5f*(ba.x+ba.z) - 0.5f*(bb.x+bb.z)) * r), 1e-3f));
            } else if (p == 1) {
                float r = __builtin_amdgcn_rcpf(ba.w - ba.y + 1.f);
                posv = __logf(fmaxf(fabsf((0.5f*(ba.y+ba.w) - 0.5f*(bb.y+bb.w)) * r), 1e-3f));
            } else if (p == 2) {
                float r = __builtin_amdgcn_rcpf(ba.z - ba.x + 1.f);
                posv = __logf((bb.z - bb.x + 1.f) * r);
            } else {
                float r = __builtin_amdgcn_rcpf(ba.w - ba.y + 1.f);
                posv = __logf((bb.w - bb.y + 1.f) * r);
            }
            posL[p * 68 + pl] = posv;
        }
        __syncthreads();

        // ---- phase B: A-fragments in registers from posL
        const int plB = w * 16 + m;
        const float pos_lo = posL[(qlow ? 0 : 1) * 68 + plB];
        const float pos_hi = posL[(qlow ? 2 : 3) * 68 + plB];

        unsigned hp0[4], lp0[4], hp1[4], lp1[4];
        #pragma unroll
        for (int fi = 0; fi < 4; ++fi) {
            float x0 = fmaxf(__sinf(fmaf(w100[2*fi],     pos_lo, phase)), 0.f);
            float x1 = fmaxf(__sinf(fmaf(w100[2*fi + 1], pos_lo, phase)), 0.f);
            unsigned u0 = fbits(x0), u1 = fbits(x1);
            unsigned r0 = fbits(x0 - bitsf(u0 & 0xFFFF0000u));
            unsigned r1 = fbits(x1 - bitsf(u1 & 0xFFFF0000u));
            hp0[fi] = (u0 >> 16) | (u1 & 0xFFFF0000u);
            lp0[fi] = (r0 >> 16) | (r1 & 0xFFFF0000u);
            float y0 = fmaxf(__sinf(fmaf(w100[2*fi],     pos_hi, phase)), 0.f);
            float y1 = fmaxf(__sinf(fmaf(w100[2*fi + 1], pos_hi, phase)), 0.f);
            unsigned v0 = fbits(y0), v1 = fbits(y1);
            unsigned s0r = fbits(y0 - bitsf(v0 & 0xFFFF0000u));
            unsigned s1r = fbits(y1 - bitsf(v1 & 0xFFFF0000u));
            hp1[fi] = (v0 >> 16) | (v1 & 0xFFFF0000u);
            lp1[fi] = (s0r >> 16) | (s1r & 0xFFFF0000u);
        }
        union { uint4v u; short8 s; } cH0, cL0, cH1, cL1;
        cH0.u = (uint4v){hp0[0], hp0[1], hp0[2], hp0[3]};
        cL0.u = (uint4v){lp0[0], lp0[1], lp0[2], lp0[3]};
        cH1.u = (uint4v){hp1[0], hp1[1], hp1[2], hp1[3]};
        cL1.u = (uint4v){lp1[0], lp1[1], lp1[2], lp1[3]};

        floatx4 acc = {0.f, 0.f, 0.f, 0.f};
        acc = mfma16(cH0.s, bH0, acc);
        acc = mfma16(cH1.s, bH1, acc);
        acc = mfma16(cH0.s, bL0, acc);
        acc = mfma16(cH1.s, bL1, acc);
        acc = mfma16(cL0.s, bH0, acc);
        acc = mfma16(cL1.s, bH1, acc);

        // C: row = pair-local w*16 + quad*4 + r, col = group m
        #pragma unroll
        for (int r = 0; r < 4; ++r)
            stg[m * 68 + w * 16 + quad * 4 + r] =
                (_Float16)__logf(fmaxf(acc[r] + bpv, 1e-6f));
        __syncthreads();   // stg ready; also posL reads of this chunk complete

        const int g2 = tid >> 4, c16 = tid & 15;
        *(half4*)(out + (long long)g2 * 524288 + pb + c16 * 4) =
            *(const half4*)&stg[g2 * 68 + c16 * 4];
        // next phase A writes posL (not stg) -> safe; next stg write is after
        // the next barrier -> store reads above are protected.
    }
}

// ---------------------------------------------------------------------------
// Fused scores + bias + softmax + output GEMM (r10, verified).
// ---------------------------------------------------------------------------
template <int NC>
__device__ __forceinline__ void attn_body(
    int g, int bx,
    const unsigned short* __restrict__ qk, int pA, int pB0,
    const _Float16* __restrict__ bias,
    const unsigned short* __restrict__ vt, int cc0,
    const float* __restrict__ b_conv, float* __restrict__ outp,
    unsigned short* wpack, float* redA, float* redB)
{
    constexpr int NCOL = NC * 64;
    constexpr int WS = NCOL + 8;
    constexpr int SHIFT = (NC == 16) ? 10 : 9;

    const int bm = bx * 16;
    const int tid = threadIdx.x;
    const int lane = tid & 63;
    const int w = tid >> 6;
    const int m = lane & 15;
    const int quad = lane >> 4;

    _Float16* bb = (_Float16*)wpack;
    {
        const _Float16* bsrc = bias + (long long)g * 524288 + (long long)bm * NCOL;
        #pragma unroll
        for (int i = 0; i < (16 * NCOL) / (256 * 8); ++i) {
            const int idx = (i * 256 + tid) * 8;
            const int row = idx >> SHIFT;
            const int col = idx & (NCOL - 1);
            *(int4*)(bb + row * WS + col) = *(const int4*)(bsrc + idx);
        }
    }

    const unsigned short* abase = qk + ((long long)(g * 96 + pA)) * 1024;
    short8 aq0 = *(const short8*)(abase + lane * 8);
    short8 aq1 = *(const short8*)(abase + 512 + lane * 8);

    const unsigned short* bptr = qk + ((long long)(g * 96 + pB0 + w)) * 1024 + lane * 8;
    short8 B0[2], B1[2];
    B0[0] = *(const short8*)bptr;
    B1[0] = *(const short8*)(bptr + 512);
    B0[1] = *(const short8*)(bptr + 4096);
    B1[1] = *(const short8*)(bptr + 4096 + 512);

    __syncthreads();   // bias staged

    const _Float16* brow = bb + (quad * 4) * WS + w * 16 + m;

    float v[NC][4];
    #pragma unroll
    for (int c = 0; c < NC; ++c) {
        float bv[4];
        #pragma unroll
        for (int r = 0; r < 4; ++r)
            bv[r] = (float)brow[r * WS + c * 64];
        floatx4 acc = {0.f, 0.f, 0.f, 0.f};
        acc = mfma16(aq0, B0[c & 1], acc);
        acc = mfma16(aq1, B1[c & 1], acc);
        if (c + 2 < NC) {
            const unsigned short* nb = bptr + (long long)(c + 2) * 4096;
            B0[c & 1] = *(const short8*)nb;
            B1[c & 1] = *(const short8*)(nb + 512);
        }
        #pragma unroll
        for (int r = 0; r < 4; ++r)
            v[c][r] = fmaf(0.125f, acc[r], bv[r]);
    }

    const unsigned short* vptr = vt + ((long long)(g * 24 + cc0)) * 4096
                               + w * 1024 + lane * 8;
    short8 V0[2], V1[2];
    V0[0] = *(const short8*)vptr;
    V1[0] = *(const short8*)(vptr + 512);
    V0[1] = *(const short8*)(vptr + 4096);
    V1[1] = *(const short8*)(vptr + 4096 + 512);

    float rmax[4];
    #pragma unroll
    for (int r = 0; r < 4; ++r) {
        float mx = v[0][r];
        #pragma unroll
        for (int c = 1; c < NC; ++c) mx = fmaxf(mx, v[c][r]);
        #pragma unroll
        for (int off = 1; off < 16; off <<= 1)
            mx = fmaxf(mx, __shfl_xor(mx, off, 64));
        rmax[r] = mx;
    }
    if (m == 0) {
        #pragma unroll
        for (int r = 0; r < 4; ++r) redA[w * 16 + quad * 4 + r] = rmax[r];
    }
    __syncthreads();
    #pragma unroll
    for (int r = 0; r < 4; ++r)
        rmax[r] = fmaxf(fmaxf(redA[quad*4+r], redA[16 + quad*4+r]),
                        fmaxf(redA[32 + quad*4+r], redA[48 + quad*4+r]));

    float rsum[4] = {0.f, 0.f, 0.f, 0.f};
    #pragma unroll
    for (int c = 0; c < NC; ++c)
        #pragma unroll
        for (int r = 0; r < 4; ++r) {
            v[c][r] = __expf(v[c][r] - rmax[r]);
            rsum[r] += v[c][r];
        }
    #pragma unroll
    for (int r = 0; r < 4; ++r)
        #pragma unroll
        for (int off = 1; off < 16; off <<= 1)
            rsum[r] += __shfl_xor(rsum[r], off, 64);
    if (m == 0) {
        #pragma unroll
        for (int r = 0; r < 4; ++r) redB[w * 16 + quad * 4 + r] = rsum[r];
    }
    __syncthreads();   // all bias reads complete before wpack overwrite
    float rinv[4];
    #pragma unroll
    for (int r = 0; r < 4; ++r)
        rinv[r] = 1.f / (redB[quad*4+r] + redB[16 + quad*4+r] +
                         redB[32 + quad*4+r] + redB[48 + quad*4+r]);

    #pragma unroll
    for (int c = 0; c < NC; ++c)
        #pragma unroll
        for (int r = 0; r < 4; ++r)
            wpack[(quad * 4 + r) * WS + c * 64 + w * 16 + m] =
                f32_bf16_rne(v[c][r] * rinv[r]);

    __syncthreads();   // wpack visible

    floatx4 oacc = {0.f, 0.f, 0.f, 0.f};
    const unsigned short* awp = wpack + m * WS + quad * 8;
    #pragma unroll
    for (int kc = 0; kc < NC; ++kc) {
        short8 a0 = *(const short8*)(awp + kc * 64);
        short8 a1 = *(const short8*)(awp + kc * 64 + 32);
        oacc = mfma16(a0, V0[kc & 1], oacc);
        oacc = mfma16(a1, V1[kc & 1], oacc);
        if (kc + 2 < NC) {
            const unsigned short* nv = vptr + (long long)(kc + 2) * 4096;
            V0[kc & 1] = *(const short8*)nv;
            V1[kc & 1] = *(const short8*)(nv + 512);
        }
    }

    const int o = w * 16 + m;
    const float bc = b_conv[g * 64 + o];
    __syncthreads();   // wpack weight reads done
    float* ot = (float*)wpack;         // 16 x 68 floats
    #pragma unroll
    for (int r = 0; r < 4; ++r)
        ot[(quad * 4 + r) * 68 + o] = oacc[r] + bc;
    __syncthreads();
    const int orow = tid >> 4, oc4 = (tid & 15) * 4;
    float4 ov = *(const float4*)&ot[orow * 68 + oc4];
    *(float4*)(outp + (long long)(bm + orow) * 1024 + g * 64 + oc4) = ov;
}

__global__ __launch_bounds__(256) void attn_out_kernel(
    const unsigned short* __restrict__ qk_pack,
    const _Float16* __restrict__ bias_gt, const _Float16* __restrict__ bias_ctx,
    const unsigned short* __restrict__ vt_pack, const float* __restrict__ b_conv,
    float* __restrict__ out_gt, float* __restrict__ out_ctx)
{
    __shared__ __align__(16) unsigned short wpack[16 * 1032];
    __shared__ float redA[64], redB[64];

    const int bx = blockIdx.x;
    if (bx < 512) {
        const int rb = bx & 31;
        attn_body<16>(bx >> 5, rb, qk_pack, /*pA=*/rb, /*pB0=*/32,
                      bias_gt, vt_pack, /*cc0=*/8, b_conv, out_gt,
                      wpack, redA, redB);
    } else {
        const int b2 = bx - 512;
        const int rb = b2 & 63;
        attn_body<8>(b2 >> 6, rb, qk_pack, /*pA=*/32 + rb, /*pB0=*/0,
                     bias_ctx, vt_pack, /*cc0=*/0, b_conv, out_ctx,
                     wpack, redA, redB);
    }
}

// ---------------------------------------------------------------------------
extern "C" void kernel_launch(void* const* d_in, const int* in_sizes, int n_in,
                              void* d_out, int out_size, void* d_ws, size_t ws_size,
                              hipStream_t stream)
{
    const float* feat     = (const float*)d_in[0];
    const float* ctx_feat = (const float*)d_in[1];
    const float* box      = (const float*)d_in[2];
    const float* ctx_box  = (const float*)d_in[3];
    const float* w_fc_gt  = (const float*)d_in[4];
    const float* b_fc_gt  = (const float*)d_in[5];
    const float* w_fc_ctx = (const float*)d_in[6];
    const float* b_fc_ctx = (const float*)d_in[7];
    const float* w_pos_gt = (const float*)d_in[8];
    const float* b_pos_gt = (const float*)d_in[9];
    const float* w_pos_ctx= (const float*)d_in[10];
    const float* b_pos_ctx= (const float*)d_in[11];
    const float* w_conv   = (const float*)d_in[12];
    const float* b_conv   = (const float*)d_in[13];

    float* ws = (float*)d_ws;
    unsigned short* in_bf   = (unsigned short*)ws;           // 1572864 s
    unsigned short* ctx_bf  = in_bf + 524288LL;
    unsigned short* qk_pack = in_bf + 1572864LL;             // 1572864 s
    _Float16* bias_gt  = (_Float16*)(ws + 1572864LL);        // 8388608 h
    _Float16* bias_ctx = (_Float16*)(ws + 5767168LL);        // 8388608 h
    unsigned short* wconv_bf = (unsigned short*)(ws + 9961472LL);   // 1048576 s
    unsigned short* vt_pack  = (unsigned short*)(ws + 10485760LL);  // 1572864 s
    unsigned short* wfcgt_bf = (unsigned short*)(ws + 11272192LL);  // 1048576 s
    unsigned short* wfcctx_bf= wfcgt_bf + 1048576LL;                // 1048576 s

    float* out_gt  = (float*)d_out;
    float* out_ctx = (float*)d_out + 524288LL;

    // 1) casts only (memory-bound, short) — the only producer posproj needs
    hipLaunchKernelGGL(cast_kernel, dim3(4608), dim3(256), 0, stream,
                       feat, in_bf,
                       ctx_feat, ctx_bf,
                       w_fc_gt, wfcgt_bf,
                       w_fc_ctx, wfcctx_bf,
                       w_conv, wconv_bf);

    // 2) fused pos_bias (VALU/trans) + direct-fragment GEMMs (MFMA/L2), i%6
    hipLaunchKernelGGL(posproj_kernel, dim3(4864), dim3(256), 0, stream,
                       box, ctx_box, w_pos_gt, b_pos_gt, w_pos_ctx, b_pos_ctx,
                       bias_gt, bias_ctx,
                       in_bf, wfcgt_bf, wfcctx_bf, b_fc_gt, b_fc_ctx, qk_pack,
                       wconv_bf, vt_pack);

    // 3) fused scores+softmax+output, both directions
    hipLaunchKernelGGL(attn_out_kernel, dim3(1536), dim3(256), 0, stream,
                       qk_pack, bias_gt, bias_ctx, vt_pack, b_conv, out_gt, out_ctx);
}

// Round 3
// 148.598 us; speedup vs baseline: 1.5388x; 1.5388x over previous
//
#include <hip/hip_runtime.h>
#include <math.h>

// M=512, N=1024, G=16, D=64, C=1024. All GEMM-shaped work on bf16 MFMA 16x16x32.
// pos_bias uses a bf16 hi/lo split MFMA (rounds 4/6: plain bf16 dot error
// ~2e-4 sign-flips entries in log-clip floor rows -> absmax 0.205).
//
// Round 15: r14's direct-global GEMM reverted (129us: 16 scattered lines/load,
// 1-deep prefetch, latency-bound; MfmaUtil 3.9%). Back to r13's staged GEMM
// (18KB LDS — r1's "36KB" diagnosis was wrong, 18KB allows 8 blocks/CU).
// New: max-free softmax. softmax(log p + s) = p*e^s / sum(p*e^s), and
// 0.125*scores in +-1, p >= 1e-6 -> exp args in [-15,2]: no max needed.
//   - prep stores p = clip(pos,1e-6) (no log)
//   - attn: v = exp2(0.125*log2e * acc) * p; normalization deferred to the
//     output epilogue (rinv per output row); redA max pass + 2 barriers gone.
//   - bias read / wpack write are same-address per-thread -> single ushort
//     type (bit-cast) keeps intra-thread ordering without a barrier.
//
// qk_pack[g][p][part][lane][8shorts]: X[row][col], row=p*16+(lane&15),
// col=part*32+(lane>>4)*8+j (g-slice base g*64); p: q rows p=row>>4 (0..31),
// k rows 32+(row-512)>>4 (32..95). vt_pack[g][cc][p][part][lane][8]: p=o>>4.
//
// Workspace (float offsets), total 12,320,768 floats = 49.3 MB:
//   [0,1572864)        : shorts: in_bf (feat 524288 + ctx 1048576), qk_pack (1572864)
//   [1572864,5767168)  : bias_gt  fp16 (16,512,1024)   [now stores p, not log p]
//   [5767168,9961472)  : bias_ctx fp16 (16,1024,512)
//   [9961472,10485760) : wconv_bf (1048576 s)
//   [10485760,11272192): vt_pack (1572864 s)
//   [11272192,12320768): wfcgt_bf + wfcctx_bf

typedef __attribute__((ext_vector_type(8))) short short8;   // 8 bf16 = 4 VGPRs
typedef __attribute__((ext_vector_type(4))) float floatx4;
typedef __attribute__((ext_vector_type(4))) _Float16 half4;
typedef __attribute__((ext_vector_type(4))) unsigned uint4v;

__device__ inline unsigned short f32_bf16_rne(float x) {
    union { float f; unsigned u; } v; v.f = x;
    unsigned u = v.u;
    return (unsigned short)((u + 0x7fffu + ((u >> 16) & 1u)) >> 16);
}

__device__ inline unsigned fbits(float x) {
    union { float f; unsigned u; } v; v.f = x; return v.u;
}
__device__ inline float bitsf(unsigned u) {
    union { unsigned u; float f; } v; v.u = u; return v.f;
}
__device__ inline float h16f(unsigned short u) {
    union { unsigned short u; _Float16 h; } v; v.u = u; return (float)v.h;
}

__device__ __forceinline__ floatx4 mfma16(short8 a, short8 b, floatx4 c) {
    return __builtin_amdgcn_mfma_f32_16x16x32_bf16(a, b, c, 0, 0, 0);
}

// ---------------------------------------------------------------------------
// 64x64 tile NT bf16 GEMM core with FRAGMENT-PACKED output (r10, verified).
// ---------------------------------------------------------------------------
__device__ __forceinline__ void gemm_tile_pack(
    const unsigned short* __restrict__ Ab, int lda,
    const unsigned short* __restrict__ Bb, int ldb, int K,
    unsigned short* __restrict__ out_base,
    const float* __restrict__ biasvec,
    unsigned short* As, unsigned short* Bs)
{
    const int tid = threadIdx.x;
    const int lr = tid >> 3;          // 0..31 (8 lanes/row)
    const int lk = (tid & 7) * 8;     // 0..56
    const int lane = tid & 63;
    const int wave = tid >> 6;
    const int qr = (wave >> 1) * 32;
    const int qc = (wave & 1) * 32;
    const int m = lane & 15;
    const int quad = lane >> 4;

    const unsigned short* Ap  = Ab + (long long)lr * lda + lk;
    const unsigned short* Ap2 = Ap + 32LL * lda;
    const unsigned short* Bp  = Bb + (long long)lr * ldb + lk;
    const unsigned short* Bp2 = Bp + 32LL * ldb;
    unsigned short* AsW  = As + lr * 72 + lk;
    unsigned short* AsW2 = As + (lr + 32) * 72 + lk;
    unsigned short* BsW  = Bs + lr * 72 + lk;
    unsigned short* BsW2 = Bs + (lr + 32) * 72 + lk;
    const unsigned short* a0p = As + (qr + m) * 72 + quad * 8;
    const unsigned short* b0p = Bs + (qc + m) * 72 + quad * 8;

    floatx4 acc00 = {0.f,0.f,0.f,0.f}, acc01 = {0.f,0.f,0.f,0.f};
    floatx4 acc10 = {0.f,0.f,0.f,0.f}, acc11 = {0.f,0.f,0.f,0.f};

    int4 pa0 = *(const int4*)Ap;
    int4 pa1 = *(const int4*)Ap2;
    int4 pb0 = *(const int4*)Bp;
    int4 pb1 = *(const int4*)Bp2;
    int4 qa0 = *(const int4*)(Ap + 64);
    int4 qa1 = *(const int4*)(Ap2 + 64);
    int4 qb0 = *(const int4*)(Bp + 64);
    int4 qb1 = *(const int4*)(Bp2 + 64);

    for (int k0 = 0; ; ) {
        __syncthreads();
        *(int4*)AsW  = pa0;
        *(int4*)AsW2 = pa1;
        *(int4*)BsW  = pb0;
        *(int4*)BsW2 = pb1;
        __syncthreads();
        pa0 = qa0; pa1 = qa1; pb0 = qb0; pb1 = qb1;
        const int kf = k0 + 128;
        if (kf < K) {
            qa0 = *(const int4*)(Ap + kf);
            qa1 = *(const int4*)(Ap2 + kf);
            qb0 = *(const int4*)(Bp + kf);
            qb1 = *(const int4*)(Bp2 + kf);
        }
        #pragma unroll
        for (int kk = 0; kk < 64; kk += 32) {
            short8 a0 = *(const short8*)(a0p + kk);
            short8 a1 = *(const short8*)(a0p + 16 * 72 + kk);
            short8 b0 = *(const short8*)(b0p + kk);
            short8 b1 = *(const short8*)(b0p + 16 * 72 + kk);
            acc00 = mfma16(a0, b0, acc00);
            acc01 = mfma16(a0, b1, acc01);
            acc10 = mfma16(a1, b0, acc10);
            acc11 = mfma16(a1, b1, acc11);
        }
        k0 += 64;
        if (k0 >= K) break;
    }

    float bias0 = 0.f, bias1 = 0.f;
    if (biasvec) { bias0 = biasvec[qc + m]; bias1 = biasvec[qc + 16 + m]; }

    __syncthreads();
    const floatx4 accs[2][2] = { {acc00, acc01}, {acc10, acc11} };
    #pragma unroll
    for (int i = 0; i < 2; ++i)
        #pragma unroll
        for (int r = 0; r < 4; ++r) {
            const int lrow = qr + i * 16 + quad * 4 + r;
            #pragma unroll
            for (int j = 0; j < 2; ++j) {
                const int lcol = qc + j * 16 + m;
                float val = accs[i][j][r] + (j ? bias1 : bias0);
                As[lrow * 72 + lcol] = f32_bf16_rne(val);
            }
        }
    __syncthreads();
    #pragma unroll
    for (int h = 0; h < 2; ++h) {
        const int f = h * 2048 + tid * 8;
        const int lanep = (f >> 3) & 63;
        const int part = (f >> 9) & 1;
        const int ploc = f >> 10;
        const int row = ploc * 16 + (lanep & 15);
        const int col = part * 32 + ((lanep >> 4) << 3);
        short8 v8 = *(const short8*)&As[row * 72 + col];
        *(short8*)(out_base + f) = v8;
    }
}

// ---------------------------------------------------------------------------
// Cast-only kernel: exact grid, no guards. 512 + 4*1024 = 4608 blocks.
// ---------------------------------------------------------------------------
__global__ __launch_bounds__(256) void cast_kernel(
    const float* __restrict__ s0, unsigned short* __restrict__ d0,
    const float* __restrict__ s1, unsigned short* __restrict__ d1,
    const float* __restrict__ s2, unsigned short* __restrict__ d2,
    const float* __restrict__ s3, unsigned short* __restrict__ d3,
    const float* __restrict__ s4, unsigned short* __restrict__ d4)
{
    int bc = blockIdx.x;
    const float* s; unsigned short* d;
    if (bc < 512)       { s = s0; d = d0; }
    else if (bc < 1536) { s = s1; d = d1; bc -= 512; }
    else if (bc < 2560) { s = s2; d = d2; bc -= 1536; }
    else if (bc < 3584) { s = s3; d = d3; bc -= 2560; }
    else                { s = s4; d = d4; bc -= 3584; }
    const int idx = (bc * 256 + threadIdx.x) * 4;
    float4 v = *(const float4*)(s + idx);
    ushort4 o;
    o.x = f32_bf16_rne(v.x); o.y = f32_bf16_rne(v.y);
    o.z = f32_bf16_rne(v.z); o.w = f32_bf16_rne(v.w);
    *(ushort4*)(d + idx) = o;
}

// ---------------------------------------------------------------------------
// Fused pos_bias + projvt kernel (r13 structure, staged GEMM, 18KB LDS).
// 4864 blocks: i%6==0 (i<4608) -> GEMM tile (768), else pos_bias chunk (4096).
// ---------------------------------------------------------------------------
__global__ __launch_bounds__(256) void posproj_kernel(
    const float* __restrict__ box, const float* __restrict__ ctx_box,
    const float* __restrict__ w_gt, const float* __restrict__ b_gt,
    const float* __restrict__ w_ctx, const float* __restrict__ b_ctx,
    _Float16* __restrict__ bias_gt, _Float16* __restrict__ bias_ctx,
    const unsigned short* __restrict__ in_bf, const unsigned short* __restrict__ wgt,
    const unsigned short* __restrict__ wctx,
    const float* __restrict__ bgt, const float* __restrict__ bctx,
    unsigned short* __restrict__ qk_pack,
    const unsigned short* __restrict__ wconv, unsigned short* __restrict__ vt_pack)
{
    __shared__ __align__(16) unsigned short smem[64 * 72 * 2];
    const int i = blockIdx.x;

    if (i < 4608 && (i % 6) == 0) {      // -------- GEMM branch (768 blocks)
        const int gi = i / 6;            // 0..767
        const int z = gi / 384;
        const int rem = gi - z * 384;
        const int g = rem / 24;
        const int cc = rem - g * 24;     // 0..23
        unsigned short* As = smem;
        unsigned short* Bs = smem + 64 * 72;
        if (z == 0) {
            const int bm = cc * 64;
            const unsigned short* B = (bm < 512) ? wgt : wctx;
            const float* bias = (bm < 512) ? bgt : bctx;
            gemm_tile_pack(in_bf + (long long)bm * 1024, 1024,
                           B + (long long)g * 65536, 1024, 1024,
                           qk_pack + ((long long)g * 96 + cc * 4) * 1024,
                           bias + g * 64, As, Bs);
        } else {
            gemm_tile_pack(wconv + (long long)g * 65536, 1024,
                           in_bf + (long long)cc * 65536, 1024, 1024,
                           vt_pack + ((long long)g * 24 + cc) * 4096,
                           nullptr, As, Bs);
        }
        return;
    }

    // -------- pos_bias branch: 256 pairs per block (4096 blocks)
    const int pi = (i < 4608) ? (i - i / 6 - 1) : (i - 768);   // 0..4095
    const bool first = (pi < 2048);
    const long long blk = first ? pi : (pi - 2048);
    const float* boxA = first ? box : ctx_box;
    const float* boxB = first ? ctx_box : box;
    const float* w_pos = first ? w_gt : w_ctx;
    const float* b_pos = first ? b_gt : b_ctx;
    _Float16* out = first ? bias_gt : bias_ctx;
    const int shift = first ? 10 : 9;

    // carve pos-branch LDS out of smem
    unsigned short* BsH = smem;                       // 16*72 shorts
    unsigned short* BsL = smem + 16 * 72;             // 16*72 shorts
    float* posL = (float*)(smem + 32 * 72);           // [p][pair_local], stride 68
    _Float16* stg = (_Float16*)(posL + 4 * 68);       // 16*68 halves

    const int tid = threadIdx.x;

    {   // stage B: w_pos (16x64 fp32) -> bf16 hi + lo (trunc split, packed)
        const int g = tid >> 4;
        const int d = (tid & 15) * 4;
        float4 wv = *(const float4*)(w_pos + g * 64 + d);
        unsigned u0 = fbits(wv.x), u1 = fbits(wv.y);
        unsigned u2 = fbits(wv.z), u3 = fbits(wv.w);
        unsigned r0 = fbits(wv.x - bitsf(u0 & 0xFFFF0000u));
        unsigned r1 = fbits(wv.y - bitsf(u1 & 0xFFFF0000u));
        unsigned r2 = fbits(wv.z - bitsf(u2 & 0xFFFF0000u));
        unsigned r3 = fbits(wv.w - bitsf(u3 & 0xFFFF0000u));
        uint2 hv, lv;
        hv.x = (u0 >> 16) | (u1 & 0xFFFF0000u);
        hv.y = (u2 >> 16) | (u3 & 0xFFFF0000u);
        lv.x = (r0 >> 16) | (r1 & 0xFFFF0000u);
        lv.y = (r2 >> 16) | (r3 & 0xFFFF0000u);
        *(uint2*)&BsH[g * 72 + d] = hv;
        *(uint2*)&BsL[g * 72 + d] = lv;
    }
    __syncthreads();

    const int lane = tid & 63;
    const int w = tid >> 6;
    const int m = lane & 15;
    const int quad = lane >> 4;
    const bool qlow = (quad < 2);
    const float phase = (quad & 1) ? 1.57079632679f : 0.0f;  // cos(t)=sin(t+pi/2)
    const float bpv = b_pos[m];

    // hoist B-fragments (weights) out of the chunk loop
    const unsigned short* bpH = &BsH[m * 72 + quad * 8];
    const unsigned short* bpL = &BsL[m * 72 + quad * 8];
    short8 bH0 = *(const short8*)bpH;
    short8 bH1 = *(const short8*)(bpH + 32);
    short8 bL0 = *(const short8*)bpL;
    short8 bL1 = *(const short8*)(bpL + 32);

    const float w100[8] = {100.f, 42.169650342f, 17.782794100f, 7.498942093f,
                           3.162277660f, 1.333521432f, 0.562341325f, 0.237137371f};
    const long long pbase = blk * 256;

    for (int it = 0; it < 4; ++it) {
        const long long pb = pbase + it * 64;

        // ---- phase A: each pos component computed once (thread (pl, p))
        {
            const int pl = tid & 63;
            const int p = tid >> 6;      // wave-uniform
            const long long pair = pb + pl;
            const int i2 = (int)(pair >> shift);
            const int j2 = (int)(pair & ((1 << shift) - 1));
            float4 ba = *(const float4*)(boxA + i2 * 4);
            float4 bb = *(const float4*)(boxB + j2 * 4);
            float posv;
            if (p == 0) {
                float r = __builtin_amdgcn_rcpf(ba.z - ba.x + 1.f);
                posv = __logf(fmaxf(fabsf((0.5f*(ba.x+ba.z) - 0.5f*(bb.x+bb.z)) * r), 1e-3f));
            } else if (p == 1) {
                float r = __builtin_amdgcn_rcpf(ba.w - ba.y + 1.f);
                posv = __logf(fmaxf(fabsf((0.5f*(ba.y+ba.w) - 0.5f*(bb.y+bb.w)) * r), 1e-3f));
            } else if (p == 2) {
                float r = __builtin_amdgcn_rcpf(ba.z - ba.x + 1.f);
                posv = __logf((bb.z - bb.x + 1.f) * r);
            } else {
                float r = __builtin_amdgcn_rcpf(ba.w - ba.y + 1.f);
                posv = __logf((bb.w - bb.y + 1.f) * r);
            }
            posL[p * 68 + pl] = posv;
        }
        __syncthreads();

        // ---- phase B: A-fragments in registers from posL
        const int plB = w * 16 + m;
        const float pos_lo = posL[(qlow ? 0 : 1) * 68 + plB];
        const float pos_hi = posL[(qlow ? 2 : 3) * 68 + plB];

        unsigned hp0[4], lp0[4], hp1[4], lp1[4];
        #pragma unroll
        for (int fi = 0; fi < 4; ++fi) {
            float x0 = fmaxf(__sinf(fmaf(w100[2*fi],     pos_lo, phase)), 0.f);
            float x1 = fmaxf(__sinf(fmaf(w100[2*fi + 1], pos_lo, phase)), 0.f);
            unsigned u0 = fbits(x0), u1 = fbits(x1);
            unsigned r0 = fbits(x0 - bitsf(u0 & 0xFFFF0000u));
            unsigned r1 = fbits(x1 - bitsf(u1 & 0xFFFF0000u));
            hp0[fi] = (u0 >> 16) | (u1 & 0xFFFF0000u);
            lp0[fi] = (r0 >> 16) | (r1 & 0xFFFF0000u);
            float y0 = fmaxf(__sinf(fmaf(w100[2*fi],     pos_hi, phase)), 0.f);
            float y1 = fmaxf(__sinf(fmaf(w100[2*fi + 1], pos_hi, phase)), 0.f);
            unsigned v0 = fbits(y0), v1 = fbits(y1);
            unsigned s0r = fbits(y0 - bitsf(v0 & 0xFFFF0000u));
            unsigned s1r = fbits(y1 - bitsf(v1 & 0xFFFF0000u));
            hp1[fi] = (v0 >> 16) | (v1 & 0xFFFF0000u);
            lp1[fi] = (s0r >> 16) | (s1r & 0xFFFF0000u);
        }
        union { uint4v u; short8 s; } cH0, cL0, cH1, cL1;
        cH0.u = (uint4v){hp0[0], hp0[1], hp0[2], hp0[3]};
        cL0.u = (uint4v){lp0[0], lp0[1], lp0[2], lp0[3]};
        cH1.u = (uint4v){hp1[0], hp1[1], hp1[2], hp1[3]};
        cL1.u = (uint4v){lp1[0], lp1[1], lp1[2], lp1[3]};

        floatx4 acc = {0.f, 0.f, 0.f, 0.f};
        acc = mfma16(cH0.s, bH0, acc);
        acc = mfma16(cH1.s, bH1, acc);
        acc = mfma16(cH0.s, bL0, acc);
        acc = mfma16(cH1.s, bL1, acc);
        acc = mfma16(cL0.s, bH0, acc);
        acc = mfma16(cL1.s, bH1, acc);

        // C: row = pair-local w*16 + quad*4 + r, col = group m
        // store p = clip(pos,1e-6) directly (softmax identity: no log needed)
        #pragma unroll
        for (int r = 0; r < 4; ++r)
            stg[m * 68 + w * 16 + quad * 4 + r] =
                (_Float16)fmaxf(acc[r] + bpv, 1e-6f);
        __syncthreads();   // stg ready; also posL reads of this chunk complete

        const int g2 = tid >> 4, c16 = tid & 15;
        *(half4*)(out + (long long)g2 * 524288 + pb + c16 * 4) =
            *(const half4*)&stg[g2 * 68 + c16 * 4];
        // next phase A writes posL (not stg) -> safe; next stg write is after
        // the next barrier -> store reads above are protected.
    }
}

// ---------------------------------------------------------------------------
// Fused scores + p-weighted max-free softmax + output GEMM.
// w = p*exp(s/8) (unnormalized) stored bf16; normalization folded into the
// output epilogue. 4 barriers (was 6), no row-max pass.
// ---------------------------------------------------------------------------
template <int NC>
__device__ __forceinline__ void attn_body(
    int g, int bx,
    const unsigned short* __restrict__ qk, int pA, int pB0,
    const _Float16* __restrict__ bias,
    const unsigned short* __restrict__ vt, int cc0,
    const float* __restrict__ b_conv, float* __restrict__ outp,
    unsigned short* wpack, float* redB)
{
    constexpr int NCOL = NC * 64;
    constexpr int WS = NCOL + 8;
    constexpr int SHIFT = (NC == 16) ? 10 : 9;

    const int bm = bx * 16;
    const int tid = threadIdx.x;
    const int lane = tid & 63;
    const int w = tid >> 6;
    const int m = lane & 15;
    const int quad = lane >> 4;

    {   // stage p-table (fp16) into wpack region
        const _Float16* bsrc = bias + (long long)g * 524288 + (long long)bm * NCOL;
        _Float16* bb = (_Float16*)wpack;
        #pragma unroll
        for (int i = 0; i < (16 * NCOL) / (256 * 8); ++i) {
            const int idx = (i * 256 + tid) * 8;
            const int row = idx >> SHIFT;
            const int col = idx & (NCOL - 1);
            *(int4*)(bb + row * WS + col) = *(const int4*)(bsrc + idx);
        }
    }

    const unsigned short* abase = qk + ((long long)(g * 96 + pA)) * 1024;
    short8 aq0 = *(const short8*)(abase + lane * 8);
    short8 aq1 = *(const short8*)(abase + 512 + lane * 8);

    const unsigned short* bptr = qk + ((long long)(g * 96 + pB0 + w)) * 1024 + lane * 8;
    short8 B0[2], B1[2];
    B0[0] = *(const short8*)bptr;
    B1[0] = *(const short8*)(bptr + 512);
    B0[1] = *(const short8*)(bptr + 4096);
    B1[1] = *(const short8*)(bptr + 4096 + 512);

    __syncthreads();   // p staged

    // ---- scores: pure MFMA loop
    float v[NC][4];
    #pragma unroll
    for (int c = 0; c < NC; ++c) {
        floatx4 acc = {0.f, 0.f, 0.f, 0.f};
        acc = mfma16(aq0, B0[c & 1], acc);
        acc = mfma16(aq1, B1[c & 1], acc);
        if (c + 2 < NC) {
            const unsigned short* nb = bptr + (long long)(c + 2) * 4096;
            B0[c & 1] = *(const short8*)nb;
            B1[c & 1] = *(const short8*)(nb + 512);
        }
        #pragma unroll
        for (int r = 0; r < 4; ++r)
            v[c][r] = acc[r];
    }

    const unsigned short* vptr = vt + ((long long)(g * 24 + cc0)) * 4096
                               + w * 1024 + lane * 8;
    short8 V0[2], V1[2];
    V0[0] = *(const short8*)vptr;
    V1[0] = *(const short8*)(vptr + 512);
    V0[1] = *(const short8*)(vptr + 4096);
    V1[1] = *(const short8*)(vptr + 4096 + 512);

    // ---- max-free: e = p * exp2(0.125*log2e * s); same-address read->write
    // per thread (wpack slot (quad*4+r)*WS + c*64 + w*16 + m), ushort typed.
    const int slot0 = (quad * 4) * WS + w * 16 + m;
    float rsum[4] = {0.f, 0.f, 0.f, 0.f};
    #pragma unroll
    for (int c = 0; c < NC; ++c)
        #pragma unroll
        for (int r = 0; r < 4; ++r) {
            const int a = slot0 + r * WS + c * 64;
            float p = h16f(wpack[a]);
            float e = exp2f(v[c][r] * 0.18033688f) * p;
            rsum[r] += e;
            wpack[a] = f32_bf16_rne(e);
        }
    #pragma unroll
    for (int r = 0; r < 4; ++r)
        #pragma unroll
        for (int off = 1; off < 16; off <<= 1)
            rsum[r] += __shfl_xor(rsum[r], off, 64);
    if (m == 0) {
        #pragma unroll
        for (int r = 0; r < 4; ++r) redB[w * 16 + quad * 4 + r] = rsum[r];
    }
    __syncthreads();   // wpack weights + redB visible

    float rinv[4];
    #pragma unroll
    for (int r = 0; r < 4; ++r)
        rinv[r] = 1.f / (redB[quad*4+r] + redB[16 + quad*4+r] +
                         redB[32 + quad*4+r] + redB[48 + quad*4+r]);

    floatx4 oacc = {0.f, 0.f, 0.f, 0.f};
    const unsigned short* awp = wpack + m * WS + quad * 8;
    #pragma unroll
    for (int kc = 0; kc < NC; ++kc) {
        short8 a0 = *(const short8*)(awp + kc * 64);
        short8 a1 = *(const short8*)(awp + kc * 64 + 32);
        oacc = mfma16(a0, V0[kc & 1], oacc);
        oacc = mfma16(a1, V1[kc & 1], oacc);
        if (kc + 2 < NC) {
            const unsigned short* nv = vptr + (long long)(kc + 2) * 4096;
            V0[kc & 1] = *(const short8*)nv;
            V1[kc & 1] = *(const short8*)(nv + 512);
        }
    }

    const int o = w * 16 + m;
    const float bc = b_conv[g * 64 + o];
    __syncthreads();   // wpack weight reads done
    float* ot = (float*)wpack;         // 16 x 68 floats
    #pragma unroll
    for (int r = 0; r < 4; ++r)
        ot[(quad * 4 + r) * 68 + o] = fmaf(oacc[r], rinv[r], bc);
    __syncthreads();
    const int orow = tid >> 4, oc4 = (tid & 15) * 4;
    float4 ov = *(const float4*)&ot[orow * 68 + oc4];
    *(float4*)(outp + (long long)(bm + orow) * 1024 + g * 64 + oc4) = ov;
}

__global__ __launch_bounds__(256) void attn_out_kernel(
    const unsigned short* __restrict__ qk_pack,
    const _Float16* __restrict__ bias_gt, const _Float16* __restrict__ bias_ctx,
    const unsigned short* __restrict__ vt_pack, const float* __restrict__ b_conv,
    float* __restrict__ out_gt, float* __restrict__ out_ctx)
{
    __shared__ __align__(16) unsigned short wpack[16 * 1032];
    __shared__ float redB[64];

    const int bx = blockIdx.x;
    if (bx < 512) {
        const int rb = bx & 31;
        attn_body<16>(bx >> 5, rb, qk_pack, /*pA=*/rb, /*pB0=*/32,
                      bias_gt, vt_pack, /*cc0=*/8, b_conv, out_gt,
                      wpack, redB);
    } else {
        const int b2 = bx - 512;
        const int rb = b2 & 63;
        attn_body<8>(b2 >> 6, rb, qk_pack, /*pA=*/32 + rb, /*pB0=*/0,
                     bias_ctx, vt_pack, /*cc0=*/0, b_conv, out_ctx,
                     wpack, redB);
    }
}

// ---------------------------------------------------------------------------
extern "C" void kernel_launch(void* const* d_in, const int* in_sizes, int n_in,
                              void* d_out, int out_size, void* d_ws, size_t ws_size,
                              hipStream_t stream)
{
    const float* feat     = (const float*)d_in[0];
    const float* ctx_feat = (const float*)d_in[1];
    const float* box      = (const float*)d_in[2];
    const float* ctx_box  = (const float*)d_in[3];
    const float* w_fc_gt  = (const float*)d_in[4];
    const float* b_fc_gt  = (const float*)d_in[5];
    const float* w_fc_ctx = (const float*)d_in[6];
    const float* b_fc_ctx = (const float*)d_in[7];
    const float* w_pos_gt = (const float*)d_in[8];
    const float* b_pos_gt = (const float*)d_in[9];
    const float* w_pos_ctx= (const float*)d_in[10];
    const float* b_pos_ctx= (const float*)d_in[11];
    const float* w_conv   = (const float*)d_in[12];
    const float* b_conv   = (const float*)d_in[13];

    float* ws = (float*)d_ws;
    unsigned short* in_bf   = (unsigned short*)ws;           // 1572864 s
    unsigned short* ctx_bf  = in_bf + 524288LL;
    unsigned short* qk_pack = in_bf + 1572864LL;             // 1572864 s
    _Float16* bias_gt  = (_Float16*)(ws + 1572864LL);        // 8388608 h
    _Float16* bias_ctx = (_Float16*)(ws + 5767168LL);        // 8388608 h
    unsigned short* wconv_bf = (unsigned short*)(ws + 9961472LL);   // 1048576 s
    unsigned short* vt_pack  = (unsigned short*)(ws + 10485760LL);  // 1572864 s
    unsigned short* wfcgt_bf = (unsigned short*)(ws + 11272192LL);  // 1048576 s
    unsigned short* wfcctx_bf= wfcgt_bf + 1048576LL;                // 1048576 s

    float* out_gt  = (float*)d_out;
    float* out_ctx = (float*)d_out + 524288LL;

    // 1) casts only (memory-bound, short) — the only producer posproj needs
    hipLaunchKernelGGL(cast_kernel, dim3(4608), dim3(256), 0, stream,
                       feat, in_bf,
                       ctx_feat, ctx_bf,
                       w_fc_gt, wfcgt_bf,
                       w_fc_ctx, wfcctx_bf,
                       w_conv, wconv_bf);

    // 2) fused pos_bias (VALU/trans) + staged GEMMs (MFMA/LDS), i%6 interleave
    hipLaunchKernelGGL(posproj_kernel, dim3(4864), dim3(256), 0, stream,
                       box, ctx_box, w_pos_gt, b_pos_gt, w_pos_ctx, b_pos_ctx,
                       bias_gt, bias_ctx,
                       in_bf, wfcgt_bf, wfcctx_bf, b_fc_gt, b_fc_ctx, qk_pack,
                       wconv_bf, vt_pack);

    // 3) fused scores + max-free softmax + output, both directions
    hipLaunchKernelGGL(attn_out_kernel, dim3(1536), dim3(256), 0, stream,
                       qk_pack, bias_gt, bias_ctx, vt_pack, b_conv, out_gt, out_ctx);
}

// Round 4
// 147.632 us; speedup vs baseline: 1.5489x; 1.0065x over previous
//
#include <hip/hip_runtime.h>
#include <math.h>

// M=512, N=1024, G=16, D=64, C=1024. All GEMM-shaped work on bf16 MFMA 16x16x32.
// pos_bias uses a bf16 hi/lo split MFMA (rounds 4/6: plain bf16 dot error
// ~2e-4 sign-flips entries in log-clip floor rows -> absmax 0.205).
//
// Round 16: budget arithmetic across r13/r14/r15 pins attn_out at ~44us (it
// hides just under the harness's 45us workspace-poison fills). attn's compute
// is ~2us; its cost is ~290MB of panel re-reads (each block re-reads its
// group's 128KB K-panel + 128KB V-panel; 16-32 blocks/group) ~= 46us at HBM.
// Panels per group = 384KB -> fit a 4MB per-XCD L2. Fix = group->XCD pinning:
//   - attn: bx -> (g = bx&15, rb = bx>>4) so blockIdx%8 == g%8 (T1 heuristic)
//   - posproj GEMM slots: i%48<8 (8 slots/48-window = one per XCD, 768 total);
//     slot XCD class j carries tiles with g%8==j (g = j + 8*(k&1)) so qk/vt
//     panels are WRITTEN into the same XCD L2 that attn READS them from.
//   - max-free softmax (r15): softmax(log p + s) = p*e^s / sum(p*e^s);
//     prep stores p=clip(pos,1e-6); normalization deferred to epilogue.
//
// qk_pack[g][p][part][lane][8shorts]: X[row][col], row=p*16+(lane&15),
// col=part*32+(lane>>4)*8+j (g-slice base g*64); p: q rows p=row>>4 (0..31),
// k rows 32+(row-512)>>4 (32..95). vt_pack[g][cc][p][part][lane][8]: p=o>>4.
//
// Workspace (float offsets), total 12,320,768 floats = 49.3 MB:
//   [0,1572864)        : shorts: in_bf (feat 524288 + ctx 1048576), qk_pack (1572864)
//   [1572864,5767168)  : bias_gt  fp16 (16,512,1024)   [stores p, not log p]
//   [5767168,9961472)  : bias_ctx fp16 (16,1024,512)
//   [9961472,10485760) : wconv_bf (1048576 s)
//   [10485760,11272192): vt_pack (1572864 s)
//   [11272192,12320768): wfcgt_bf + wfcctx_bf

typedef __attribute__((ext_vector_type(8))) short short8;   // 8 bf16 = 4 VGPRs
typedef __attribute__((ext_vector_type(4))) float floatx4;
typedef __attribute__((ext_vector_type(4))) _Float16 half4;
typedef __attribute__((ext_vector_type(4))) unsigned uint4v;

__device__ inline unsigned short f32_bf16_rne(float x) {
    union { float f; unsigned u; } v; v.f = x;
    unsigned u = v.u;
    return (unsigned short)((u + 0x7fffu + ((u >> 16) & 1u)) >> 16);
}

__device__ inline unsigned fbits(float x) {
    union { float f; unsigned u; } v; v.f = x; return v.u;
}
__device__ inline float bitsf(unsigned u) {
    union { unsigned u; float f; } v; v.u = u; return v.f;
}
__device__ inline float h16f(unsigned short u) {
    union { unsigned short u; _Float16 h; } v; v.u = u; return (float)v.h;
}

__device__ __forceinline__ floatx4 mfma16(short8 a, short8 b, floatx4 c) {
    return __builtin_amdgcn_mfma_f32_16x16x32_bf16(a, b, c, 0, 0, 0);
}

// ---------------------------------------------------------------------------
// 64x64 tile NT bf16 GEMM core with FRAGMENT-PACKED output (r10, verified).
// ---------------------------------------------------------------------------
__device__ __forceinline__ void gemm_tile_pack(
    const unsigned short* __restrict__ Ab, int lda,
    const unsigned short* __restrict__ Bb, int ldb, int K,
    unsigned short* __restrict__ out_base,
    const float* __restrict__ biasvec,
    unsigned short* As, unsigned short* Bs)
{
    const int tid = threadIdx.x;
    const int lr = tid >> 3;          // 0..31 (8 lanes/row)
    const int lk = (tid & 7) * 8;     // 0..56
    const int lane = tid & 63;
    const int wave = tid >> 6;
    const int qr = (wave >> 1) * 32;
    const int qc = (wave & 1) * 32;
    const int m = lane & 15;
    const int quad = lane >> 4;

    const unsigned short* Ap  = Ab + (long long)lr * lda + lk;
    const unsigned short* Ap2 = Ap + 32LL * lda;
    const unsigned short* Bp  = Bb + (long long)lr * ldb + lk;
    const unsigned short* Bp2 = Bp + 32LL * ldb;
    unsigned short* AsW  = As + lr * 72 + lk;
    unsigned short* AsW2 = As + (lr + 32) * 72 + lk;
    unsigned short* BsW  = Bs + lr * 72 + lk;
    unsigned short* BsW2 = Bs + (lr + 32) * 72 + lk;
    const unsigned short* a0p = As + (qr + m) * 72 + quad * 8;
    const unsigned short* b0p = Bs + (qc + m) * 72 + quad * 8;

    floatx4 acc00 = {0.f,0.f,0.f,0.f}, acc01 = {0.f,0.f,0.f,0.f};
    floatx4 acc10 = {0.f,0.f,0.f,0.f}, acc11 = {0.f,0.f,0.f,0.f};

    int4 pa0 = *(const int4*)Ap;
    int4 pa1 = *(const int4*)Ap2;
    int4 pb0 = *(const int4*)Bp;
    int4 pb1 = *(const int4*)Bp2;
    int4 qa0 = *(const int4*)(Ap + 64);
    int4 qa1 = *(const int4*)(Ap2 + 64);
    int4 qb0 = *(const int4*)(Bp + 64);
    int4 qb1 = *(const int4*)(Bp2 + 64);

    for (int k0 = 0; ; ) {
        __syncthreads();
        *(int4*)AsW  = pa0;
        *(int4*)AsW2 = pa1;
        *(int4*)BsW  = pb0;
        *(int4*)BsW2 = pb1;
        __syncthreads();
        pa0 = qa0; pa1 = qa1; pb0 = qb0; pb1 = qb1;
        const int kf = k0 + 128;
        if (kf < K) {
            qa0 = *(const int4*)(Ap + kf);
            qa1 = *(const int4*)(Ap2 + kf);
            qb0 = *(const int4*)(Bp + kf);
            qb1 = *(const int4*)(Bp2 + kf);
        }
        #pragma unroll
        for (int kk = 0; kk < 64; kk += 32) {
            short8 a0 = *(const short8*)(a0p + kk);
            short8 a1 = *(const short8*)(a0p + 16 * 72 + kk);
            short8 b0 = *(const short8*)(b0p + kk);
            short8 b1 = *(const short8*)(b0p + 16 * 72 + kk);
            acc00 = mfma16(a0, b0, acc00);
            acc01 = mfma16(a0, b1, acc01);
            acc10 = mfma16(a1, b0, acc10);
            acc11 = mfma16(a1, b1, acc11);
        }
        k0 += 64;
        if (k0 >= K) break;
    }

    float bias0 = 0.f, bias1 = 0.f;
    if (biasvec) { bias0 = biasvec[qc + m]; bias1 = biasvec[qc + 16 + m]; }

    __syncthreads();
    const floatx4 accs[2][2] = { {acc00, acc01}, {acc10, acc11} };
    #pragma unroll
    for (int i = 0; i < 2; ++i)
        #pragma unroll
        for (int r = 0; r < 4; ++r) {
            const int lrow = qr + i * 16 + quad * 4 + r;
            #pragma unroll
            for (int j = 0; j < 2; ++j) {
                const int lcol = qc + j * 16 + m;
                float val = accs[i][j][r] + (j ? bias1 : bias0);
                As[lrow * 72 + lcol] = f32_bf16_rne(val);
            }
        }
    __syncthreads();
    #pragma unroll
    for (int h = 0; h < 2; ++h) {
        const int f = h * 2048 + tid * 8;
        const int lanep = (f >> 3) & 63;
        const int part = (f >> 9) & 1;
        const int ploc = f >> 10;
        const int row = ploc * 16 + (lanep & 15);
        const int col = part * 32 + ((lanep >> 4) << 3);
        short8 v8 = *(const short8*)&As[row * 72 + col];
        *(short8*)(out_base + f) = v8;
    }
}

// ---------------------------------------------------------------------------
// Cast-only kernel: exact grid, no guards. 512 + 4*1024 = 4608 blocks.
// ---------------------------------------------------------------------------
__global__ __launch_bounds__(256) void cast_kernel(
    const float* __restrict__ s0, unsigned short* __restrict__ d0,
    const float* __restrict__ s1, unsigned short* __restrict__ d1,
    const float* __restrict__ s2, unsigned short* __restrict__ d2,
    const float* __restrict__ s3, unsigned short* __restrict__ d3,
    const float* __restrict__ s4, unsigned short* __restrict__ d4)
{
    int bc = blockIdx.x;
    const float* s; unsigned short* d;
    if (bc < 512)       { s = s0; d = d0; }
    else if (bc < 1536) { s = s1; d = d1; bc -= 512; }
    else if (bc < 2560) { s = s2; d = d2; bc -= 1536; }
    else if (bc < 3584) { s = s3; d = d3; bc -= 2560; }
    else                { s = s4; d = d4; bc -= 3584; }
    const int idx = (bc * 256 + threadIdx.x) * 4;
    float4 v = *(const float4*)(s + idx);
    ushort4 o;
    o.x = f32_bf16_rne(v.x); o.y = f32_bf16_rne(v.y);
    o.z = f32_bf16_rne(v.z); o.w = f32_bf16_rne(v.w);
    *(ushort4*)(d + idx) = o;
}

// ---------------------------------------------------------------------------
// Fused pos_bias + projvt kernel. 4864 blocks. GEMM slots: i%48 < 8 (i<4608),
// 96 windows x 8 = 768 tiles; slot class j=i%8 (the dispatch XCD heuristic)
// carries tiles with g%8==j so panel writes land on attn's reader XCD.
// Everything else -> pos_bias chunk (4096 blocks).
// ---------------------------------------------------------------------------
__global__ __launch_bounds__(256) void posproj_kernel(
    const float* __restrict__ box, const float* __restrict__ ctx_box,
    const float* __restrict__ w_gt, const float* __restrict__ b_gt,
    const float* __restrict__ w_ctx, const float* __restrict__ b_ctx,
    _Float16* __restrict__ bias_gt, _Float16* __restrict__ bias_ctx,
    const unsigned short* __restrict__ in_bf, const unsigned short* __restrict__ wgt,
    const unsigned short* __restrict__ wctx,
    const float* __restrict__ bgt, const float* __restrict__ bctx,
    unsigned short* __restrict__ qk_pack,
    const unsigned short* __restrict__ wconv, unsigned short* __restrict__ vt_pack)
{
    __shared__ __align__(16) unsigned short smem[64 * 72 * 2];
    const int i = blockIdx.x;

    int pi;
    if (i < 4608) {
        const int k48 = i / 48;
        const int r48 = i - k48 * 48;
        if (r48 < 8) {                   // -------- GEMM branch (768 blocks)
            const int j = r48;           // == i%8 == XCD class
            const int k = k48;           // 0..95
            const int g = j + 8 * (k & 1);       // g%8 == j
            const int rest = k >> 1;             // 0..47
            const int z = rest / 24;
            const int cc = rest - z * 24;        // 0..23
            unsigned short* As = smem;
            unsigned short* Bs = smem + 64 * 72;
            if (z == 0) {
                const int bm = cc * 64;
                const unsigned short* B = (bm < 512) ? wgt : wctx;
                const float* bias = (bm < 512) ? bgt : bctx;
                gemm_tile_pack(in_bf + (long long)bm * 1024, 1024,
                               B + (long long)g * 65536, 1024, 1024,
                               qk_pack + ((long long)g * 96 + cc * 4) * 1024,
                               bias + g * 64, As, Bs);
            } else {
                gemm_tile_pack(wconv + (long long)g * 65536, 1024,
                               in_bf + (long long)cc * 65536, 1024, 1024,
                               vt_pack + ((long long)g * 24 + cc) * 4096,
                               nullptr, As, Bs);
            }
            return;
        }
        pi = i - k48 * 8 - 8;            // pos blocks 0..3839
    } else {
        pi = i - 768;                    // pos blocks 3840..4095
    }

    // -------- pos_bias branch: 256 pairs per block (4096 blocks)
    const bool first = (pi < 2048);
    const long long blk = first ? pi : (pi - 2048);
    const float* boxA = first ? box : ctx_box;
    const float* boxB = first ? ctx_box : box;
    const float* w_pos = first ? w_gt : w_ctx;
    const float* b_pos = first ? b_gt : b_ctx;
    _Float16* out = first ? bias_gt : bias_ctx;
    const int shift = first ? 10 : 9;

    // carve pos-branch LDS out of smem
    unsigned short* BsH = smem;                       // 16*72 shorts
    unsigned short* BsL = smem + 16 * 72;             // 16*72 shorts
    float* posL = (float*)(smem + 32 * 72);           // [p][pair_local], stride 68
    _Float16* stg = (_Float16*)(posL + 4 * 68);       // 16*68 halves

    const int tid = threadIdx.x;

    {   // stage B: w_pos (16x64 fp32) -> bf16 hi + lo (trunc split, packed)
        const int g = tid >> 4;
        const int d = (tid & 15) * 4;
        float4 wv = *(const float4*)(w_pos + g * 64 + d);
        unsigned u0 = fbits(wv.x), u1 = fbits(wv.y);
        unsigned u2 = fbits(wv.z), u3 = fbits(wv.w);
        unsigned r0 = fbits(wv.x - bitsf(u0 & 0xFFFF0000u));
        unsigned r1 = fbits(wv.y - bitsf(u1 & 0xFFFF0000u));
        unsigned r2 = fbits(wv.z - bitsf(u2 & 0xFFFF0000u));
        unsigned r3 = fbits(wv.w - bitsf(u3 & 0xFFFF0000u));
        uint2 hv, lv;
        hv.x = (u0 >> 16) | (u1 & 0xFFFF0000u);
        hv.y = (u2 >> 16) | (u3 & 0xFFFF0000u);
        lv.x = (r0 >> 16) | (r1 & 0xFFFF0000u);
        lv.y = (r2 >> 16) | (r3 & 0xFFFF0000u);
        *(uint2*)&BsH[g * 72 + d] = hv;
        *(uint2*)&BsL[g * 72 + d] = lv;
    }
    __syncthreads();

    const int lane = tid & 63;
    const int w = tid >> 6;
    const int m = lane & 15;
    const int quad = lane >> 4;
    const bool qlow = (quad < 2);
    const float phase = (quad & 1) ? 1.57079632679f : 0.0f;  // cos(t)=sin(t+pi/2)
    const float bpv = b_pos[m];

    // hoist B-fragments (weights) out of the chunk loop
    const unsigned short* bpH = &BsH[m * 72 + quad * 8];
    const unsigned short* bpL = &BsL[m * 72 + quad * 8];
    short8 bH0 = *(const short8*)bpH;
    short8 bH1 = *(const short8*)(bpH + 32);
    short8 bL0 = *(const short8*)bpL;
    short8 bL1 = *(const short8*)(bpL + 32);

    const float w100[8] = {100.f, 42.169650342f, 17.782794100f, 7.498942093f,
                           3.162277660f, 1.333521432f, 0.562341325f, 0.237137371f};
    const long long pbase = blk * 256;

    for (int it = 0; it < 4; ++it) {
        const long long pb = pbase + it * 64;

        // ---- phase A: each pos component computed once (thread (pl, p))
        {
            const int pl = tid & 63;
            const int p = tid >> 6;      // wave-uniform
            const long long pair = pb + pl;
            const int i2 = (int)(pair >> shift);
            const int j2 = (int)(pair & ((1 << shift) - 1));
            float4 ba = *(const float4*)(boxA + i2 * 4);
            float4 bb = *(const float4*)(boxB + j2 * 4);
            float posv;
            if (p == 0) {
                float r = __builtin_amdgcn_rcpf(ba.z - ba.x + 1.f);
                posv = __logf(fmaxf(fabsf((0.5f*(ba.x+ba.z) - 0.5f*(bb.x+bb.z)) * r), 1e-3f));
            } else if (p == 1) {
                float r = __builtin_amdgcn_rcpf(ba.w - ba.y + 1.f);
                posv = __logf(fmaxf(fabsf((0.5f*(ba.y+ba.w) - 0.5f*(bb.y+bb.w)) * r), 1e-3f));
            } else if (p == 2) {
                float r = __builtin_amdgcn_rcpf(ba.z - ba.x + 1.f);
                posv = __logf((bb.z - bb.x + 1.f) * r);
            } else {
                float r = __builtin_amdgcn_rcpf(ba.w - ba.y + 1.f);
                posv = __logf((bb.w - bb.y + 1.f) * r);
            }
            posL[p * 68 + pl] = posv;
        }
        __syncthreads();

        // ---- phase B: A-fragments in registers from posL
        const int plB = w * 16 + m;
        const float pos_lo = posL[(qlow ? 0 : 1) * 68 + plB];
        const float pos_hi = posL[(qlow ? 2 : 3) * 68 + plB];

        unsigned hp0[4], lp0[4], hp1[4], lp1[4];
        #pragma unroll
        for (int fi = 0; fi < 4; ++fi) {
            float x0 = fmaxf(__sinf(fmaf(w100[2*fi],     pos_lo, phase)), 0.f);
            float x1 = fmaxf(__sinf(fmaf(w100[2*fi + 1], pos_lo, phase)), 0.f);
            unsigned u0 = fbits(x0), u1 = fbits(x1);
            unsigned r0 = fbits(x0 - bitsf(u0 & 0xFFFF0000u));
            unsigned r1 = fbits(x1 - bitsf(u1 & 0xFFFF0000u));
            hp0[fi] = (u0 >> 16) | (u1 & 0xFFFF0000u);
            lp0[fi] = (r0 >> 16) | (r1 & 0xFFFF0000u);
            float y0 = fmaxf(__sinf(fmaf(w100[2*fi],     pos_hi, phase)), 0.f);
            float y1 = fmaxf(__sinf(fmaf(w100[2*fi + 1], pos_hi, phase)), 0.f);
            unsigned v0 = fbits(y0), v1 = fbits(y1);
            unsigned s0r = fbits(y0 - bitsf(v0 & 0xFFFF0000u));
            unsigned s1r = fbits(y1 - bitsf(v1 & 0xFFFF0000u));
            hp1[fi] = (v0 >> 16) | (v1 & 0xFFFF0000u);
            lp1[fi] = (s0r >> 16) | (s1r & 0xFFFF0000u);
        }
        union { uint4v u; short8 s; } cH0, cL0, cH1, cL1;
        cH0.u = (uint4v){hp0[0], hp0[1], hp0[2], hp0[3]};
        cL0.u = (uint4v){lp0[0], lp0[1], lp0[2], lp0[3]};
        cH1.u = (uint4v){hp1[0], hp1[1], hp1[2], hp1[3]};
        cL1.u = (uint4v){lp1[0], lp1[1], lp1[2], lp1[3]};

        floatx4 acc = {0.f, 0.f, 0.f, 0.f};
        acc = mfma16(cH0.s, bH0, acc);
        acc = mfma16(cH1.s, bH1, acc);
        acc = mfma16(cH0.s, bL0, acc);
        acc = mfma16(cH1.s, bL1, acc);
        acc = mfma16(cL0.s, bH0, acc);
        acc = mfma16(cL1.s, bH1, acc);

        // C: row = pair-local w*16 + quad*4 + r, col = group m
        // store p = clip(pos,1e-6) directly (softmax identity: no log needed)
        #pragma unroll
        for (int r = 0; r < 4; ++r)
            stg[m * 68 + w * 16 + quad * 4 + r] =
                (_Float16)fmaxf(acc[r] + bpv, 1e-6f);
        __syncthreads();   // stg ready; also posL reads of this chunk complete

        const int g2 = tid >> 4, c16 = tid & 15;
        *(half4*)(out + (long long)g2 * 524288 + pb + c16 * 4) =
            *(const half4*)&stg[g2 * 68 + c16 * 4];
        // next phase A writes posL (not stg) -> safe; next stg write is after
        // the next barrier -> store reads above are protected.
    }
}

// ---------------------------------------------------------------------------
// Fused scores + p-weighted max-free softmax + output GEMM (r15, verified).
// ---------------------------------------------------------------------------
template <int NC>
__device__ __forceinline__ void attn_body(
    int g, int bx,
    const unsigned short* __restrict__ qk, int pA, int pB0,
    const _Float16* __restrict__ bias,
    const unsigned short* __restrict__ vt, int cc0,
    const float* __restrict__ b_conv, float* __restrict__ outp,
    unsigned short* wpack, float* redB)
{
    constexpr int NCOL = NC * 64;
    constexpr int WS = NCOL + 8;
    constexpr int SHIFT = (NC == 16) ? 10 : 9;

    const int bm = bx * 16;
    const int tid = threadIdx.x;
    const int lane = tid & 63;
    const int w = tid >> 6;
    const int m = lane & 15;
    const int quad = lane >> 4;

    {   // stage p-table (fp16) into wpack region
        const _Float16* bsrc = bias + (long long)g * 524288 + (long long)bm * NCOL;
        _Float16* bb = (_Float16*)wpack;
        #pragma unroll
        for (int i = 0; i < (16 * NCOL) / (256 * 8); ++i) {
            const int idx = (i * 256 + tid) * 8;
            const int row = idx >> SHIFT;
            const int col = idx & (NCOL - 1);
            *(int4*)(bb + row * WS + col) = *(const int4*)(bsrc + idx);
        }
    }

    const unsigned short* abase = qk + ((long long)(g * 96 + pA)) * 1024;
    short8 aq0 = *(const short8*)(abase + lane * 8);
    short8 aq1 = *(const short8*)(abase + 512 + lane * 8);

    const unsigned short* bptr = qk + ((long long)(g * 96 + pB0 + w)) * 1024 + lane * 8;
    short8 B0[2], B1[2];
    B0[0] = *(const short8*)bptr;
    B1[0] = *(const short8*)(bptr + 512);
    B0[1] = *(const short8*)(bptr + 4096);
    B1[1] = *(const short8*)(bptr + 4096 + 512);

    __syncthreads();   // p staged

    // ---- scores: pure MFMA loop
    float v[NC][4];
    #pragma unroll
    for (int c = 0; c < NC; ++c) {
        floatx4 acc = {0.f, 0.f, 0.f, 0.f};
        acc = mfma16(aq0, B0[c & 1], acc);
        acc = mfma16(aq1, B1[c & 1], acc);
        if (c + 2 < NC) {
            const unsigned short* nb = bptr + (long long)(c + 2) * 4096;
            B0[c & 1] = *(const short8*)nb;
            B1[c & 1] = *(const short8*)(nb + 512);
        }
        #pragma unroll
        for (int r = 0; r < 4; ++r)
            v[c][r] = acc[r];
    }

    const unsigned short* vptr = vt + ((long long)(g * 24 + cc0)) * 4096
                               + w * 1024 + lane * 8;
    short8 V0[2], V1[2];
    V0[0] = *(const short8*)vptr;
    V1[0] = *(const short8*)(vptr + 512);
    V0[1] = *(const short8*)(vptr + 4096);
    V1[1] = *(const short8*)(vptr + 4096 + 512);

    // ---- max-free: e = p * exp2(0.125*log2e * s); same-address read->write
    // per thread (wpack slot (quad*4+r)*WS + c*64 + w*16 + m), ushort typed.
    const int slot0 = (quad * 4) * WS + w * 16 + m;
    float rsum[4] = {0.f, 0.f, 0.f, 0.f};
    #pragma unroll
    for (int c = 0; c < NC; ++c)
        #pragma unroll
        for (int r = 0; r < 4; ++r) {
            const int a = slot0 + r * WS + c * 64;
            float p = h16f(wpack[a]);
            float e = exp2f(v[c][r] * 0.18033688f) * p;
            rsum[r] += e;
            wpack[a] = f32_bf16_rne(e);
        }
    #pragma unroll
    for (int r = 0; r < 4; ++r)
        #pragma unroll
        for (int off = 1; off < 16; off <<= 1)
            rsum[r] += __shfl_xor(rsum[r], off, 64);
    if (m == 0) {
        #pragma unroll
        for (int r = 0; r < 4; ++r) redB[w * 16 + quad * 4 + r] = rsum[r];
    }
    __syncthreads();   // wpack weights + redB visible

    float rinv[4];
    #pragma unroll
    for (int r = 0; r < 4; ++r)
        rinv[r] = 1.f / (redB[quad*4+r] + redB[16 + quad*4+r] +
                         redB[32 + quad*4+r] + redB[48 + quad*4+r]);

    floatx4 oacc = {0.f, 0.f, 0.f, 0.f};
    const unsigned short* awp = wpack + m * WS + quad * 8;
    #pragma unroll
    for (int kc = 0; kc < NC; ++kc) {
        short8 a0 = *(const short8*)(awp + kc * 64);
        short8 a1 = *(const short8*)(awp + kc * 64 + 32);
        oacc = mfma16(a0, V0[kc & 1], oacc);
        oacc = mfma16(a1, V1[kc & 1], oacc);
        if (kc + 2 < NC) {
            const unsigned short* nv = vptr + (long long)(kc + 2) * 4096;
            V0[kc & 1] = *(const short8*)nv;
            V1[kc & 1] = *(const short8*)(nv + 512);
        }
    }

    const int o = w * 16 + m;
    const float bc = b_conv[g * 64 + o];
    __syncthreads();   // wpack weight reads done
    float* ot = (float*)wpack;         // 16 x 68 floats
    #pragma unroll
    for (int r = 0; r < 4; ++r)
        ot[(quad * 4 + r) * 68 + o] = fmaf(oacc[r], rinv[r], bc);
    __syncthreads();
    const int orow = tid >> 4, oc4 = (tid & 15) * 4;
    float4 ov = *(const float4*)&ot[orow * 68 + oc4];
    *(float4*)(outp + (long long)(bm + orow) * 1024 + g * 64 + oc4) = ov;
}

__global__ __launch_bounds__(256) void attn_out_kernel(
    const unsigned short* __restrict__ qk_pack,
    const _Float16* __restrict__ bias_gt, const _Float16* __restrict__ bias_ctx,
    const unsigned short* __restrict__ vt_pack, const float* __restrict__ b_conv,
    float* __restrict__ out_gt, float* __restrict__ out_ctx)
{
    __shared__ __align__(16) unsigned short wpack[16 * 1032];
    __shared__ float redB[64];

    // group->XCD pinning: blockIdx%8 == g%8 (matches posproj's panel writes)
    const int bx = blockIdx.x;
    if (bx < 512) {
        const int g = bx & 15;
        const int rb = bx >> 4;          // 0..31
        attn_body<16>(g, rb, qk_pack, /*pA=*/rb, /*pB0=*/32,
                      bias_gt, vt_pack, /*cc0=*/8, b_conv, out_gt,
                      wpack, redB);
    } else {
        const int b2 = bx - 512;
        const int g = b2 & 15;
        const int rb = b2 >> 4;          // 0..63
        attn_body<8>(g, rb, qk_pack, /*pA=*/32 + rb, /*pB0=*/0,
                     bias_ctx, vt_pack, /*cc0=*/0, b_conv, out_ctx,
                     wpack, redB);
    }
}

// ---------------------------------------------------------------------------
extern "C" void kernel_launch(void* const* d_in, const int* in_sizes, int n_in,
                              void* d_out, int out_size, void* d_ws, size_t ws_size,
                              hipStream_t stream)
{
    const float* feat     = (const float*)d_in[0];
    const float* ctx_feat = (const float*)d_in[1];
    const float* box      = (const float*)d_in[2];
    const float* ctx_box  = (const float*)d_in[3];
    const float* w_fc_gt  = (const float*)d_in[4];
    const float* b_fc_gt  = (const float*)d_in[5];
    const float* w_fc_ctx = (const float*)d_in[6];
    const float* b_fc_ctx = (const float*)d_in[7];
    const float* w_pos_gt = (const float*)d_in[8];
    const float* b_pos_gt = (const float*)d_in[9];
    const float* w_pos_ctx= (const float*)d_in[10];
    const float* b_pos_ctx= (const float*)d_in[11];
    const float* w_conv   = (const float*)d_in[12];
    const float* b_conv   = (const float*)d_in[13];

    float* ws = (float*)d_ws;
    unsigned short* in_bf   = (unsigned short*)ws;           // 1572864 s
    unsigned short* ctx_bf  = in_bf + 524288LL;
    unsigned short* qk_pack = in_bf + 1572864LL;             // 1572864 s
    _Float16* bias_gt  = (_Float16*)(ws + 1572864LL);        // 8388608 h
    _Float16* bias_ctx = (_Float16*)(ws + 5767168LL);        // 8388608 h
    unsigned short* wconv_bf = (unsigned short*)(ws + 9961472LL);   // 1048576 s
    unsigned short* vt_pack  = (unsigned short*)(ws + 10485760LL);  // 1572864 s
    unsigned short* wfcgt_bf = (unsigned short*)(ws + 11272192LL);  // 1048576 s
    unsigned short* wfcctx_bf= wfcgt_bf + 1048576LL;                // 1048576 s

    float* out_gt  = (float*)d_out;
    float* out_ctx = (float*)d_out + 524288LL;

    // 1) casts only (memory-bound, short) — the only producer posproj needs
    hipLaunchKernelGGL(cast_kernel, dim3(4608), dim3(256), 0, stream,
                       feat, in_bf,
                       ctx_feat, ctx_bf,
                       w_fc_gt, wfcgt_bf,
                       w_fc_ctx, wfcctx_bf,
                       w_conv, wconv_bf);

    // 2) fused pos_bias (VALU/trans) + staged GEMMs, XCD-pinned slot scheme
    hipLaunchKernelGGL(posproj_kernel, dim3(4864), dim3(256), 0, stream,
                       box, ctx_box, w_pos_gt, b_pos_gt, w_pos_ctx, b_pos_ctx,
                       bias_gt, bias_ctx,
                       in_bf, wfcgt_bf, wfcctx_bf, b_fc_gt, b_fc_ctx, qk_pack,
                       wconv_bf, vt_pack);

    // 3) fused scores + max-free softmax + output, group->XCD pinned
    hipLaunchKernelGGL(attn_out_kernel, dim3(1536), dim3(256), 0, stream,
                       qk_pack, bias_gt, bias_ctx, vt_pack, b_conv, out_gt, out_ctx);
}

// Round 5
// 147.443 us; speedup vs baseline: 1.5509x; 1.0013x over previous
//
#include <hip/hip_runtime.h>
#include <math.h>

// M=512, N=1024, G=16, D=64, C=1024. All GEMM-shaped work on bf16 MFMA 16x16x32.
// pos_bias uses a bf16 hi/lo split MFMA (rounds 4/6: plain bf16 dot error
// ~2e-4 sign-flips entries in log-clip floor rows -> absmax 0.205).
//
// Round 17: attn restructured to 32 rows/block, 512 threads (8 waves: ws=w>>2
// row-set, wq=w&3 k-quarter). Halves K/V panel re-read traffic (~300->~170MB)
// and amortizes stage/barrier/reduce overheads 2x; works whether attn is
// BW-bound or overhead-bound (r16's XCD pinning was a no-op => cache-mapping
// tricks unreliable). exp fused into the score loop (kills v[NC][4] = 64
// VGPRs; keeps 2 blocks/CU at 512 threads). posproj phase A inlined per-lane
// (box row i2 is chunk-uniform; quad-select + 1 rcp + 2 logs), posL LDS
// exchange + 1 barrier/iter removed; stg double-buffered.
//   1) cast_kernel   : fp32->bf16 casts (exact 4608-block grid)
//   2) posproj_kernel: pos_bias (4096) + staged GEMMs (768), i%48<8 slots
//   3) attn_out_kernel: 768 blocks x 512 threads, 32 rows/block.
//
// qk_pack[g][p][part][lane][8shorts]: X[row][col], row=p*16+(lane&15),
// col=part*32+(lane>>4)*8+j (g-slice base g*64); p: q rows p=row>>4 (0..31),
// k rows 32+(row-512)>>4 (32..95). vt_pack[g][cc][p][part][lane][8]: p=o>>4.
//
// Workspace (float offsets), total 12,320,768 floats = 49.3 MB:
//   [0,1572864)        : shorts: in_bf (feat 524288 + ctx 1048576), qk_pack (1572864)
//   [1572864,5767168)  : bias_gt  fp16 (16,512,1024)   [stores p, not log p]
//   [5767168,9961472)  : bias_ctx fp16 (16,1024,512)
//   [9961472,10485760) : wconv_bf (1048576 s)
//   [10485760,11272192): vt_pack (1572864 s)
//   [11272192,12320768): wfcgt_bf + wfcctx_bf

typedef __attribute__((ext_vector_type(8))) short short8;   // 8 bf16 = 4 VGPRs
typedef __attribute__((ext_vector_type(4))) float floatx4;
typedef __attribute__((ext_vector_type(4))) _Float16 half4;
typedef __attribute__((ext_vector_type(4))) unsigned uint4v;

__device__ inline unsigned short f32_bf16_rne(float x) {
    union { float f; unsigned u; } v; v.f = x;
    unsigned u = v.u;
    return (unsigned short)((u + 0x7fffu + ((u >> 16) & 1u)) >> 16);
}

__device__ inline unsigned fbits(float x) {
    union { float f; unsigned u; } v; v.f = x; return v.u;
}
__device__ inline float bitsf(unsigned u) {
    union { unsigned u; float f; } v; v.u = u; return v.f;
}
__device__ inline float h16f(unsigned short u) {
    union { unsigned short u; _Float16 h; } v; v.u = u; return (float)v.h;
}

__device__ __forceinline__ floatx4 mfma16(short8 a, short8 b, floatx4 c) {
    return __builtin_amdgcn_mfma_f32_16x16x32_bf16(a, b, c, 0, 0, 0);
}

// ---------------------------------------------------------------------------
// 64x64 tile NT bf16 GEMM core with FRAGMENT-PACKED output (r10, verified).
// ---------------------------------------------------------------------------
__device__ __forceinline__ void gemm_tile_pack(
    const unsigned short* __restrict__ Ab, int lda,
    const unsigned short* __restrict__ Bb, int ldb, int K,
    unsigned short* __restrict__ out_base,
    const float* __restrict__ biasvec,
    unsigned short* As, unsigned short* Bs)
{
    const int tid = threadIdx.x;
    const int lr = tid >> 3;          // 0..31 (8 lanes/row)
    const int lk = (tid & 7) * 8;     // 0..56
    const int lane = tid & 63;
    const int wave = tid >> 6;
    const int qr = (wave >> 1) * 32;
    const int qc = (wave & 1) * 32;
    const int m = lane & 15;
    const int quad = lane >> 4;

    const unsigned short* Ap  = Ab + (long long)lr * lda + lk;
    const unsigned short* Ap2 = Ap + 32LL * lda;
    const unsigned short* Bp  = Bb + (long long)lr * ldb + lk;
    const unsigned short* Bp2 = Bp + 32LL * ldb;
    unsigned short* AsW  = As + lr * 72 + lk;
    unsigned short* AsW2 = As + (lr + 32) * 72 + lk;
    unsigned short* BsW  = Bs + lr * 72 + lk;
    unsigned short* BsW2 = Bs + (lr + 32) * 72 + lk;
    const unsigned short* a0p = As + (qr + m) * 72 + quad * 8;
    const unsigned short* b0p = Bs + (qc + m) * 72 + quad * 8;

    floatx4 acc00 = {0.f,0.f,0.f,0.f}, acc01 = {0.f,0.f,0.f,0.f};
    floatx4 acc10 = {0.f,0.f,0.f,0.f}, acc11 = {0.f,0.f,0.f,0.f};

    int4 pa0 = *(const int4*)Ap;
    int4 pa1 = *(const int4*)Ap2;
    int4 pb0 = *(const int4*)Bp;
    int4 pb1 = *(const int4*)Bp2;
    int4 qa0 = *(const int4*)(Ap + 64);
    int4 qa1 = *(const int4*)(Ap2 + 64);
    int4 qb0 = *(const int4*)(Bp + 64);
    int4 qb1 = *(const int4*)(Bp2 + 64);

    for (int k0 = 0; ; ) {
        __syncthreads();
        *(int4*)AsW  = pa0;
        *(int4*)AsW2 = pa1;
        *(int4*)BsW  = pb0;
        *(int4*)BsW2 = pb1;
        __syncthreads();
        pa0 = qa0; pa1 = qa1; pb0 = qb0; pb1 = qb1;
        const int kf = k0 + 128;
        if (kf < K) {
            qa0 = *(const int4*)(Ap + kf);
            qa1 = *(const int4*)(Ap2 + kf);
            qb0 = *(const int4*)(Bp + kf);
            qb1 = *(const int4*)(Bp2 + kf);
        }
        #pragma unroll
        for (int kk = 0; kk < 64; kk += 32) {
            short8 a0 = *(const short8*)(a0p + kk);
            short8 a1 = *(const short8*)(a0p + 16 * 72 + kk);
            short8 b0 = *(const short8*)(b0p + kk);
            short8 b1 = *(const short8*)(b0p + 16 * 72 + kk);
            acc00 = mfma16(a0, b0, acc00);
            acc01 = mfma16(a0, b1, acc01);
            acc10 = mfma16(a1, b0, acc10);
            acc11 = mfma16(a1, b1, acc11);
        }
        k0 += 64;
        if (k0 >= K) break;
    }

    float bias0 = 0.f, bias1 = 0.f;
    if (biasvec) { bias0 = biasvec[qc + m]; bias1 = biasvec[qc + 16 + m]; }

    __syncthreads();
    const floatx4 accs[2][2] = { {acc00, acc01}, {acc10, acc11} };
    #pragma unroll
    for (int i = 0; i < 2; ++i)
        #pragma unroll
        for (int r = 0; r < 4; ++r) {
            const int lrow = qr + i * 16 + quad * 4 + r;
            #pragma unroll
            for (int j = 0; j < 2; ++j) {
                const int lcol = qc + j * 16 + m;
                float val = accs[i][j][r] + (j ? bias1 : bias0);
                As[lrow * 72 + lcol] = f32_bf16_rne(val);
            }
        }
    __syncthreads();
    #pragma unroll
    for (int h = 0; h < 2; ++h) {
        const int f = h * 2048 + tid * 8;
        const int lanep = (f >> 3) & 63;
        const int part = (f >> 9) & 1;
        const int ploc = f >> 10;
        const int row = ploc * 16 + (lanep & 15);
        const int col = part * 32 + ((lanep >> 4) << 3);
        short8 v8 = *(const short8*)&As[row * 72 + col];
        *(short8*)(out_base + f) = v8;
    }
}

// ---------------------------------------------------------------------------
// Cast-only kernel: exact grid, no guards. 512 + 4*1024 = 4608 blocks.
// ---------------------------------------------------------------------------
__global__ __launch_bounds__(256) void cast_kernel(
    const float* __restrict__ s0, unsigned short* __restrict__ d0,
    const float* __restrict__ s1, unsigned short* __restrict__ d1,
    const float* __restrict__ s2, unsigned short* __restrict__ d2,
    const float* __restrict__ s3, unsigned short* __restrict__ d3,
    const float* __restrict__ s4, unsigned short* __restrict__ d4)
{
    int bc = blockIdx.x;
    const float* s; unsigned short* d;
    if (bc < 512)       { s = s0; d = d0; }
    else if (bc < 1536) { s = s1; d = d1; bc -= 512; }
    else if (bc < 2560) { s = s2; d = d2; bc -= 1536; }
    else if (bc < 3584) { s = s3; d = d3; bc -= 2560; }
    else                { s = s4; d = d4; bc -= 3584; }
    const int idx = (bc * 256 + threadIdx.x) * 4;
    float4 v = *(const float4*)(s + idx);
    ushort4 o;
    o.x = f32_bf16_rne(v.x); o.y = f32_bf16_rne(v.y);
    o.z = f32_bf16_rne(v.z); o.w = f32_bf16_rne(v.w);
    *(ushort4*)(d + idx) = o;
}

// ---------------------------------------------------------------------------
// Fused pos_bias + projvt kernel. 4864 blocks. GEMM slots: i%48 < 8 (i<4608),
// 96 windows x 8 = 768 tiles. pos branch: phase A inlined per-lane (no posL,
// 1 barrier/iter, stg double-buffered).
// ---------------------------------------------------------------------------
__global__ __launch_bounds__(256) void posproj_kernel(
    const float* __restrict__ box, const float* __restrict__ ctx_box,
    const float* __restrict__ w_gt, const float* __restrict__ b_gt,
    const float* __restrict__ w_ctx, const float* __restrict__ b_ctx,
    _Float16* __restrict__ bias_gt, _Float16* __restrict__ bias_ctx,
    const unsigned short* __restrict__ in_bf, const unsigned short* __restrict__ wgt,
    const unsigned short* __restrict__ wctx,
    const float* __restrict__ bgt, const float* __restrict__ bctx,
    unsigned short* __restrict__ qk_pack,
    const unsigned short* __restrict__ wconv, unsigned short* __restrict__ vt_pack)
{
    __shared__ __align__(16) unsigned short smem[64 * 72 * 2];
    const int i = blockIdx.x;

    int pi;
    if (i < 4608) {
        const int k48 = i / 48;
        const int r48 = i - k48 * 48;
        if (r48 < 8) {                   // -------- GEMM branch (768 blocks)
            const int j = r48;
            const int k = k48;           // 0..95
            const int g = j + 8 * (k & 1);
            const int rest = k >> 1;     // 0..47
            const int z = rest / 24;
            const int cc = rest - z * 24;
            unsigned short* As = smem;
            unsigned short* Bs = smem + 64 * 72;
            if (z == 0) {
                const int bm = cc * 64;
                const unsigned short* B = (bm < 512) ? wgt : wctx;
                const float* bias = (bm < 512) ? bgt : bctx;
                gemm_tile_pack(in_bf + (long long)bm * 1024, 1024,
                               B + (long long)g * 65536, 1024, 1024,
                               qk_pack + ((long long)g * 96 + cc * 4) * 1024,
                               bias + g * 64, As, Bs);
            } else {
                gemm_tile_pack(wconv + (long long)g * 65536, 1024,
                               in_bf + (long long)cc * 65536, 1024, 1024,
                               vt_pack + ((long long)g * 24 + cc) * 4096,
                               nullptr, As, Bs);
            }
            return;
        }
        pi = i - k48 * 8 - 8;            // pos blocks 0..3839
    } else {
        pi = i - 768;                    // pos blocks 3840..4095
    }

    // -------- pos_bias branch: 256 pairs per block (4096 blocks)
    const bool first = (pi < 2048);
    const long long blk = first ? pi : (pi - 2048);
    const float* boxA = first ? box : ctx_box;
    const float* boxB = first ? ctx_box : box;
    const float* w_pos = first ? w_gt : w_ctx;
    const float* b_pos = first ? b_gt : b_ctx;
    _Float16* out = first ? bias_gt : bias_ctx;
    const int shift = first ? 10 : 9;

    // carve pos-branch LDS out of smem
    unsigned short* BsH = smem;                       // 16*72 shorts
    unsigned short* BsL = smem + 16 * 72;             // 16*72 shorts
    _Float16* stg = (_Float16*)(smem + 32 * 72);      // 2 x 16*68 halves (dbuf)

    const int tid = threadIdx.x;

    {   // stage B: w_pos (16x64 fp32) -> bf16 hi + lo (trunc split, packed)
        const int g = tid >> 4;
        const int d = (tid & 15) * 4;
        float4 wv = *(const float4*)(w_pos + g * 64 + d);
        unsigned u0 = fbits(wv.x), u1 = fbits(wv.y);
        unsigned u2 = fbits(wv.z), u3 = fbits(wv.w);
        unsigned r0 = fbits(wv.x - bitsf(u0 & 0xFFFF0000u));
        unsigned r1 = fbits(wv.y - bitsf(u1 & 0xFFFF0000u));
        unsigned r2 = fbits(wv.z - bitsf(u2 & 0xFFFF0000u));
        unsigned r3 = fbits(wv.w - bitsf(u3 & 0xFFFF0000u));
        uint2 hv, lv;
        hv.x = (u0 >> 16) | (u1 & 0xFFFF0000u);
        hv.y = (u2 >> 16) | (u3 & 0xFFFF0000u);
        lv.x = (r0 >> 16) | (r1 & 0xFFFF0000u);
        lv.y = (r2 >> 16) | (r3 & 0xFFFF0000u);
        *(uint2*)&BsH[g * 72 + d] = hv;
        *(uint2*)&BsL[g * 72 + d] = lv;
    }
    __syncthreads();

    const int lane = tid & 63;
    const int w = tid >> 6;
    const int m = lane & 15;
    const int quad = lane >> 4;
    const bool qlow = (quad < 2);
    const float phase = (quad & 1) ? 1.57079632679f : 0.0f;  // cos(t)=sin(t+pi/2)
    const float bpv = b_pos[m];
    const int plB = w * 16 + m;          // pair-local 0..63

    // hoist B-fragments (weights) out of the chunk loop
    const unsigned short* bpH = &BsH[m * 72 + quad * 8];
    const unsigned short* bpL = &BsL[m * 72 + quad * 8];
    short8 bH0 = *(const short8*)bpH;
    short8 bH1 = *(const short8*)(bpH + 32);
    short8 bL0 = *(const short8*)bpL;
    short8 bL1 = *(const short8*)(bpL + 32);

    const float w100[8] = {100.f, 42.169650342f, 17.782794100f, 7.498942093f,
                           3.162277660f, 1.333521432f, 0.562341325f, 0.237137371f};
    const long long pbase = blk * 256;

    for (int it = 0; it < 4; ++it) {
        const long long pb = pbase + it * 64;

        // ---- inlined pos components: i2 is chunk-uniform; quad-select x/y
        const int i2 = (int)(pb >> shift);
        const int j2 = (int)(pb & ((1 << shift) - 1)) + plB;
        float4 ba = *(const float4*)(boxA + i2 * 4);
        float4 bb = *(const float4*)(boxB + j2 * 4);
        const float a0 = qlow ? ba.x : ba.y, a1 = qlow ? ba.z : ba.w;
        const float b0 = qlow ? bb.x : bb.y, b1 = qlow ? bb.z : bb.w;
        const float rr = __builtin_amdgcn_rcpf(a1 - a0 + 1.f);
        const float pos_lo =
            __logf(fmaxf(fabsf((0.5f*(a0+a1) - 0.5f*(b0+b1)) * rr), 1e-3f));
        const float pos_hi = __logf((b1 - b0 + 1.f) * rr);

        unsigned hp0[4], lp0[4], hp1[4], lp1[4];
        #pragma unroll
        for (int fi = 0; fi < 4; ++fi) {
            float x0 = fmaxf(__sinf(fmaf(w100[2*fi],     pos_lo, phase)), 0.f);
            float x1 = fmaxf(__sinf(fmaf(w100[2*fi + 1], pos_lo, phase)), 0.f);
            unsigned u0 = fbits(x0), u1 = fbits(x1);
            unsigned r0 = fbits(x0 - bitsf(u0 & 0xFFFF0000u));
            unsigned r1 = fbits(x1 - bitsf(u1 & 0xFFFF0000u));
            hp0[fi] = (u0 >> 16) | (u1 & 0xFFFF0000u);
            lp0[fi] = (r0 >> 16) | (r1 & 0xFFFF0000u);
            float y0 = fmaxf(__sinf(fmaf(w100[2*fi],     pos_hi, phase)), 0.f);
            float y1 = fmaxf(__sinf(fmaf(w100[2*fi + 1], pos_hi, phase)), 0.f);
            unsigned v0 = fbits(y0), v1 = fbits(y1);
            unsigned s0r = fbits(y0 - bitsf(v0 & 0xFFFF0000u));
            unsigned s1r = fbits(y1 - bitsf(v1 & 0xFFFF0000u));
            hp1[fi] = (v0 >> 16) | (v1 & 0xFFFF0000u);
            lp1[fi] = (s0r >> 16) | (s1r & 0xFFFF0000u);
        }
        union { uint4v u; short8 s; } cH0, cL0, cH1, cL1;
        cH0.u = (uint4v){hp0[0], hp0[1], hp0[2], hp0[3]};
        cL0.u = (uint4v){lp0[0], lp0[1], lp0[2], lp0[3]};
        cH1.u = (uint4v){hp1[0], hp1[1], hp1[2], hp1[3]};
        cL1.u = (uint4v){lp1[0], lp1[1], lp1[2], lp1[3]};

        floatx4 acc = {0.f, 0.f, 0.f, 0.f};
        acc = mfma16(cH0.s, bH0, acc);
        acc = mfma16(cH1.s, bH1, acc);
        acc = mfma16(cH0.s, bL0, acc);
        acc = mfma16(cH1.s, bL1, acc);
        acc = mfma16(cL0.s, bH0, acc);
        acc = mfma16(cL1.s, bH1, acc);

        // C: row = pair-local w*16 + quad*4 + r, col = group m
        // store p = clip(pos,1e-6) directly (softmax identity: no log needed)
        _Float16* s = stg + (it & 1) * 1088;
        #pragma unroll
        for (int r = 0; r < 4; ++r)
            s[m * 68 + w * 16 + quad * 4 + r] =
                (_Float16)fmaxf(acc[r] + bpv, 1e-6f);
        __syncthreads();   // stg[it&1] ready; prev buffer's reads long done

        const int g2 = tid >> 4, c16 = tid & 15;
        *(half4*)(out + (long long)g2 * 524288 + pb + c16 * 4) =
            *(const half4*)&s[g2 * 68 + c16 * 4];
    }
}

// ---------------------------------------------------------------------------
// Fused scores + p-weighted max-free softmax + output GEMM.
// 32 rows/block, 512 threads: ws = w>>2 row-set (16 rows), wq = w&3 k-quarter.
// exp fused into the score loop (no v[NC][4] array).
// ---------------------------------------------------------------------------
template <int NC>
__device__ __forceinline__ void attn_body(
    int g, int bm,
    const unsigned short* __restrict__ qk, int pA0, int pB0,
    const _Float16* __restrict__ bias,
    const unsigned short* __restrict__ vt, int cc0,
    const float* __restrict__ b_conv, float* __restrict__ outp,
    unsigned short* wpack, float* redB)
{
    constexpr int NCOL = NC * 64;
    constexpr int WS = NCOL + 8;
    constexpr int SHIFT = (NC == 16) ? 10 : 9;
    constexpr int NSTG = (32 * NCOL) / (512 * 8);

    const int tid = threadIdx.x;
    const int lane = tid & 63;
    const int w = tid >> 6;          // 0..7
    const int ws = w >> 2;           // row-set
    const int wq = w & 3;            // k-quarter
    const int m = lane & 15;
    const int quad = lane >> 4;

    {   // stage p-table (fp16, 32 x NCOL) into wpack region
        const _Float16* bsrc = bias + (long long)g * 524288 + (long long)bm * NCOL;
        _Float16* bb = (_Float16*)wpack;
        #pragma unroll
        for (int i = 0; i < NSTG; ++i) {
            const int idx = (i * 512 + tid) * 8;
            const int row = idx >> SHIFT;
            const int col = idx & (NCOL - 1);
            *(int4*)(bb + row * WS + col) = *(const int4*)(bsrc + idx);
        }
    }

    const unsigned short* abase = qk + ((long long)(g * 96 + pA0 + ws)) * 1024;
    short8 aq0 = *(const short8*)(abase + lane * 8);
    short8 aq1 = *(const short8*)(abase + 512 + lane * 8);

    const unsigned short* bptr = qk + ((long long)(g * 96 + pB0 + wq)) * 1024 + lane * 8;
    short8 B0[2], B1[2];
    B0[0] = *(const short8*)bptr;
    B1[0] = *(const short8*)(bptr + 512);
    B0[1] = *(const short8*)(bptr + 4096);
    B1[1] = *(const short8*)(bptr + 4096 + 512);

    __syncthreads();   // p staged

    // ---- fused scores + max-free exp: e = p * exp2(0.125*log2e * s)
    const int slot0 = (ws * 16 + quad * 4) * WS + wq * 16 + m;
    float rsum[4] = {0.f, 0.f, 0.f, 0.f};
    #pragma unroll
    for (int c = 0; c < NC; ++c) {
        floatx4 acc = {0.f, 0.f, 0.f, 0.f};
        acc = mfma16(aq0, B0[c & 1], acc);
        acc = mfma16(aq1, B1[c & 1], acc);
        if (c + 2 < NC) {
            const unsigned short* nb = bptr + (long long)(c + 2) * 4096;
            B0[c & 1] = *(const short8*)nb;
            B1[c & 1] = *(const short8*)(nb + 512);
        }
        #pragma unroll
        for (int r = 0; r < 4; ++r) {
            const int a = slot0 + r * WS + c * 64;
            float p = h16f(wpack[a]);
            float e = exp2f(acc[r] * 0.18033688f) * p;
            rsum[r] += e;
            wpack[a] = f32_bf16_rne(e);
        }
    }

    const unsigned short* vptr = vt + ((long long)(g * 24 + cc0)) * 4096
                               + wq * 1024 + lane * 8;
    short8 V0[2], V1[2];
    V0[0] = *(const short8*)vptr;
    V1[0] = *(const short8*)(vptr + 512);
    V0[1] = *(const short8*)(vptr + 4096);
    V1[1] = *(const short8*)(vptr + 4096 + 512);

    #pragma unroll
    for (int r = 0; r < 4; ++r)
        #pragma unroll
        for (int off = 1; off < 16; off <<= 1)
            rsum[r] += __shfl_xor(rsum[r], off, 64);
    if (m == 0) {
        #pragma unroll
        for (int r = 0; r < 4; ++r) redB[w * 16 + quad * 4 + r] = rsum[r];
    }
    __syncthreads();   // wpack weights + redB visible

    float rinv[4];
    #pragma unroll
    for (int r = 0; r < 4; ++r)
        rinv[r] = 1.f / (redB[ws*64 + quad*4+r] + redB[ws*64 + 16 + quad*4+r] +
                         redB[ws*64 + 32 + quad*4+r] + redB[ws*64 + 48 + quad*4+r]);

    floatx4 oacc = {0.f, 0.f, 0.f, 0.f};
    const unsigned short* awp = wpack + (ws * 16 + m) * WS + quad * 8;
    #pragma unroll
    for (int kc = 0; kc < NC; ++kc) {
        short8 a0 = *(const short8*)(awp + kc * 64);
        short8 a1 = *(const short8*)(awp + kc * 64 + 32);
        oacc = mfma16(a0, V0[kc & 1], oacc);
        oacc = mfma16(a1, V1[kc & 1], oacc);
        if (kc + 2 < NC) {
            const unsigned short* nv = vptr + (long long)(kc + 2) * 4096;
            V0[kc & 1] = *(const short8*)nv;
            V1[kc & 1] = *(const short8*)(nv + 512);
        }
    }

    const int o = wq * 16 + m;
    const float bc = b_conv[g * 64 + o];
    __syncthreads();   // wpack weight reads done
    float* ot = (float*)wpack;         // 32 x 68 floats
    #pragma unroll
    for (int r = 0; r < 4; ++r)
        ot[(ws * 16 + quad * 4 + r) * 68 + o] = fmaf(oacc[r], rinv[r], bc);
    __syncthreads();
    const int orow = tid >> 4, oc4 = (tid & 15) * 4;
    float4 ov = *(const float4*)&ot[orow * 68 + oc4];
    *(float4*)(outp + (long long)(bm + orow) * 1024 + g * 64 + oc4) = ov;
}

__global__ __launch_bounds__(512) void attn_out_kernel(
    const unsigned short* __restrict__ qk_pack,
    const _Float16* __restrict__ bias_gt, const _Float16* __restrict__ bias_ctx,
    const unsigned short* __restrict__ vt_pack, const float* __restrict__ b_conv,
    float* __restrict__ out_gt, float* __restrict__ out_ctx)
{
    __shared__ __align__(16) unsigned short wpack[32 * 1032];
    __shared__ float redB[128];

    const int bx = blockIdx.x;
    if (bx < 256) {
        const int g = bx & 15;
        const int rb = bx >> 4;          // 0..15 (32 rows each)
        attn_body<16>(g, rb * 32, qk_pack, /*pA0=*/2 * rb, /*pB0=*/32,
                      bias_gt, vt_pack, /*cc0=*/8, b_conv, out_gt,
                      wpack, redB);
    } else {
        const int b2 = bx - 256;
        const int g = b2 & 15;
        const int rb = b2 >> 4;          // 0..31 (32 rows each)
        attn_body<8>(g, rb * 32, qk_pack, /*pA0=*/32 + 2 * rb, /*pB0=*/0,
                     bias_ctx, vt_pack, /*cc0=*/0, b_conv, out_ctx,
                     wpack, redB);
    }
}

// ---------------------------------------------------------------------------
extern "C" void kernel_launch(void* const* d_in, const int* in_sizes, int n_in,
                              void* d_out, int out_size, void* d_ws, size_t ws_size,
                              hipStream_t stream)
{
    const float* feat     = (const float*)d_in[0];
    const float* ctx_feat = (const float*)d_in[1];
    const float* box      = (const float*)d_in[2];
    const float* ctx_box  = (const float*)d_in[3];
    const float* w_fc_gt  = (const float*)d_in[4];
    const float* b_fc_gt  = (const float*)d_in[5];
    const float* w_fc_ctx = (const float*)d_in[6];
    const float* b_fc_ctx = (const float*)d_in[7];
    const float* w_pos_gt = (const float*)d_in[8];
    const float* b_pos_gt = (const float*)d_in[9];
    const float* w_pos_ctx= (const float*)d_in[10];
    const float* b_pos_ctx= (const float*)d_in[11];
    const float* w_conv   = (const float*)d_in[12];
    const float* b_conv   = (const float*)d_in[13];

    float* ws = (float*)d_ws;
    unsigned short* in_bf   = (unsigned short*)ws;           // 1572864 s
    unsigned short* ctx_bf  = in_bf + 524288LL;
    unsigned short* qk_pack = in_bf + 1572864LL;             // 1572864 s
    _Float16* bias_gt  = (_Float16*)(ws + 1572864LL);        // 8388608 h
    _Float16* bias_ctx = (_Float16*)(ws + 5767168LL);        // 8388608 h
    unsigned short* wconv_bf = (unsigned short*)(ws + 9961472LL);   // 1048576 s
    unsigned short* vt_pack  = (unsigned short*)(ws + 10485760LL);  // 1572864 s
    unsigned short* wfcgt_bf = (unsigned short*)(ws + 11272192LL);  // 1048576 s
    unsigned short* wfcctx_bf= wfcgt_bf + 1048576LL;                // 1048576 s

    float* out_gt  = (float*)d_out;
    float* out_ctx = (float*)d_out + 524288LL;

    // 1) casts only (memory-bound, short) — the only producer posproj needs
    hipLaunchKernelGGL(cast_kernel, dim3(4608), dim3(256), 0, stream,
                       feat, in_bf,
                       ctx_feat, ctx_bf,
                       w_fc_gt, wfcgt_bf,
                       w_fc_ctx, wfcctx_bf,
                       w_conv, wconv_bf);

    // 2) fused pos_bias (VALU/trans) + staged GEMMs
    hipLaunchKernelGGL(posproj_kernel, dim3(4864), dim3(256), 0, stream,
                       box, ctx_box, w_pos_gt, b_pos_gt, w_pos_ctx, b_pos_ctx,
                       bias_gt, bias_ctx,
                       in_bf, wfcgt_bf, wfcctx_bf, b_fc_gt, b_fc_ctx, qk_pack,
                       wconv_bf, vt_pack);

    // 3) fused scores + max-free softmax + output, 32 rows/block
    hipLaunchKernelGGL(attn_out_kernel, dim3(768), dim3(512), 0, stream,
                       qk_pack, bias_gt, bias_ctx, vt_pack, b_conv, out_gt, out_ctx);
}